// Round 1
// baseline (11769.158 us; speedup 1.0000x reference)
//
#include <hip/hip_runtime.h>
#include <cstddef>

constexpr int B_ = 64, S_ = 512, E_ = 512, H_ = 8, D_ = 64, L_ = 4, O_ = 1000;
constexpr int BS_ = B_ * S_;        // 32768
constexpr int HD_ = H_ * D_;        // 512
constexpr int LOUT_ = 102;
constexpr float SCALE_ = 0.04419417382415922f;  // 1/sqrt(512)

// ---------------- embedding + mask ----------------
__global__ __launch_bounds__(256) void embed_kernel(
    const int* __restrict__ tokens, const float* __restrict__ emb,
    float* __restrict__ X) {
  int idx = blockIdx.x * 256 + threadIdx.x;  // float4 index
  int bs = idx >> 7;                         // 128 float4 per row of E=512
  int e = (idx & 127) << 2;
  int tok = tokens[bs];
  float4 v;
  if (tok == 0) {
    v = make_float4(0.f, 0.f, 0.f, 0.f);     // mask = sign(token)
  } else {
    v = *(const float4*)(emb + (size_t)tok * E_ + e);
  }
  *(float4*)(X + (size_t)bs * E_ + e) = v;
}

// ---------------- fp32 tiled GEMM ----------------
// C[M,N] = act(A[M,K] @ B + bias[N] (+ Rsd))
// BLAYOUT 0: B row-major [K,N].  BLAYOUT 1: B is [H, K, 64] (qkv weight), n = h*64 + d.
template <int BLAYOUT, int RELU, int RES>
__global__ __launch_bounds__(256) void gemm_kernel(
    const float* __restrict__ A, const float* __restrict__ Bw,
    const float* __restrict__ bias, const float* __restrict__ Rsd,
    float* __restrict__ C, int M, int N, int K) {
  __shared__ float As[16][64];  // [k][m]
  __shared__ float Bs[16][64];  // [k][n]
  int tid = threadIdx.x;
  int tx = tid & 15, ty = tid >> 4;
  int m0 = blockIdx.x * 64, n0 = blockIdx.y * 64;
  int a_row = tid >> 2, a_k = (tid & 3) << 2;
  int b_k = tid >> 4, b_n = (tid & 15) << 2;
  float acc[4][4] = {};
  for (int k0 = 0; k0 < K; k0 += 16) {
    float4 av = *(const float4*)(A + (size_t)(m0 + a_row) * K + k0 + a_k);
    As[a_k + 0][a_row] = av.x;
    As[a_k + 1][a_row] = av.y;
    As[a_k + 2][a_row] = av.z;
    As[a_k + 3][a_row] = av.w;
    float4 bv;
    if (BLAYOUT == 0) {
      bv = *(const float4*)(Bw + (size_t)(k0 + b_k) * N + n0 + b_n);
    } else {
      // element (k, n): h = n>>6, d = n&63 ; addr = (h*K + k)*64 + d
      bv = *(const float4*)(Bw + ((size_t)(n0 >> 6) * K + (k0 + b_k)) * 64 + b_n);
    }
    *(float4*)&Bs[b_k][b_n] = bv;
    __syncthreads();
#pragma unroll
    for (int kt = 0; kt < 16; ++kt) {
      float4 a4 = *(const float4*)&As[kt][ty << 2];
      float4 b4 = *(const float4*)&Bs[kt][tx << 2];
      float a[4] = {a4.x, a4.y, a4.z, a4.w};
      float b[4] = {b4.x, b4.y, b4.z, b4.w};
#pragma unroll
      for (int i = 0; i < 4; ++i)
#pragma unroll
        for (int j = 0; j < 4; ++j) acc[i][j] += a[i] * b[j];
    }
    __syncthreads();
  }
  int nb = n0 + (tx << 2);
  float4 bi = *(const float4*)(bias + nb);
  float bb[4] = {bi.x, bi.y, bi.z, bi.w};
#pragma unroll
  for (int i = 0; i < 4; ++i) {
    size_t row = (size_t)m0 + (ty << 2) + i;
    float o[4];
#pragma unroll
    for (int j = 0; j < 4; ++j) o[j] = acc[i][j] + bb[j];
    if (RES) {
      float4 rv = *(const float4*)(Rsd + row * N + nb);
      o[0] += rv.x; o[1] += rv.y; o[2] += rv.z; o[3] += rv.w;
    }
    if (RELU) {
#pragma unroll
      for (int j = 0; j < 4; ++j) o[j] = fmaxf(o[j], 0.f);
    }
    *(float4*)(C + row * N + nb) = make_float4(o[0], o[1], o[2], o[3]);
  }
}

// ---------------- flash-style attention (fp32) ----------------
// one block per (b, h, 64-row s-tile). Q/K/V layout [B,S,H,D] (row = s, stride HD).
// Writes heads IN-PLACE over Q (block loads its own Q tile to LDS first; blocks
// only ever touch their own (b,h,s-tile) slice -> safe under any schedule).
__global__ __launch_bounds__(256) void attn_kernel(
    const float* __restrict__ Q, const float* __restrict__ Kg,
    const float* __restrict__ Vg, float* __restrict__ Out) {
  __shared__ float Qs[64][65];  // [d][s]  (+1 pad: conflict-free transposed store)
  __shared__ float KV[64][65];  // [d][t]  K^T, then V^T
  __shared__ float Ss[64][65];  // [s][t]
  __shared__ float rowM[64], rowL[64], rowA[64];
  int blk = blockIdx.x;
  int stile = blk & 7, bh = blk >> 3;
  int h = bh & 7, b = bh >> 3;
  int tid = threadIdx.x, tx = tid & 15, ty = tid >> 4;
  size_t base = ((size_t)b * S_) * HD_ + (size_t)h * D_;
  int s0 = stile << 6;
  int lr = tid >> 4, ld = (tid & 15) << 2;
#pragma unroll
  for (int p = 0; p < 4; ++p) {
    int s = (p << 4) + lr;
    float4 v = *(const float4*)(Q + base + (size_t)(s0 + s) * HD_ + ld);
    Qs[ld + 0][s] = v.x; Qs[ld + 1][s] = v.y;
    Qs[ld + 2][s] = v.z; Qs[ld + 3][s] = v.w;
  }
  if (tid < 64) { rowM[tid] = -1e30f; rowL[tid] = 0.f; }
  float accO[4][4] = {};
  for (int t0 = 0; t0 < S_; t0 += 64) {
    // K tile, transposed
#pragma unroll
    for (int p = 0; p < 4; ++p) {
      int t = (p << 4) + lr;
      float4 v = *(const float4*)(Kg + base + (size_t)(t0 + t) * HD_ + ld);
      KV[ld + 0][t] = v.x; KV[ld + 1][t] = v.y;
      KV[ld + 2][t] = v.z; KV[ld + 3][t] = v.w;
    }
    __syncthreads();
    // S = Q K^T * scale
    {
      float sc[4][4] = {};
      for (int d = 0; d < 64; ++d) {
        float qa[4], kb[4];
#pragma unroll
        for (int i = 0; i < 4; ++i) qa[i] = Qs[d][(ty << 2) + i];
#pragma unroll
        for (int j = 0; j < 4; ++j) kb[j] = KV[d][(tx << 2) + j];
#pragma unroll
        for (int i = 0; i < 4; ++i)
#pragma unroll
          for (int j = 0; j < 4; ++j) sc[i][j] += qa[i] * kb[j];
      }
#pragma unroll
      for (int i = 0; i < 4; ++i)
#pragma unroll
        for (int j = 0; j < 4; ++j)
          Ss[(ty << 2) + i][(tx << 2) + j] = sc[i][j] * SCALE_;
    }
    __syncthreads();
    // online softmax (one thread per row) -- V load happens concurrently below
    if (tid < 64) {
      int r = tid;
      float mx = rowM[r];
      for (int t = 0; t < 64; ++t) mx = fmaxf(mx, Ss[r][t]);
      float alpha = expf(rowM[r] - mx);
      float l = rowL[r] * alpha;
      for (int t = 0; t < 64; ++t) {
        float e = expf(Ss[r][t] - mx);
        Ss[r][t] = e;
        l += e;
      }
      rowM[r] = mx; rowL[r] = l; rowA[r] = alpha;
    }
    // V tile, transposed, into the same buffer (K already consumed)
#pragma unroll
    for (int p = 0; p < 4; ++p) {
      int t = (p << 4) + lr;
      float4 v = *(const float4*)(Vg + base + (size_t)(t0 + t) * HD_ + ld);
      KV[ld + 0][t] = v.x; KV[ld + 1][t] = v.y;
      KV[ld + 2][t] = v.z; KV[ld + 3][t] = v.w;
    }
    __syncthreads();
    // O = diag(alpha) O + P V
    {
      float alpha[4];
#pragma unroll
      for (int i = 0; i < 4; ++i) alpha[i] = rowA[(ty << 2) + i];
#pragma unroll
      for (int i = 0; i < 4; ++i)
#pragma unroll
        for (int j = 0; j < 4; ++j) accO[i][j] *= alpha[i];
      for (int t = 0; t < 64; ++t) {
        float p4[4], v4[4];
#pragma unroll
        for (int i = 0; i < 4; ++i) p4[i] = Ss[(ty << 2) + i][t];
#pragma unroll
        for (int j = 0; j < 4; ++j) v4[j] = KV[(tx << 2) + j][t];
#pragma unroll
        for (int i = 0; i < 4; ++i)
#pragma unroll
          for (int j = 0; j < 4; ++j) accO[i][j] += p4[i] * v4[j];
      }
    }
    __syncthreads();
  }
#pragma unroll
  for (int i = 0; i < 4; ++i) {
    int s = (ty << 2) + i;
    float inv = 1.f / rowL[s];
    float4 o = make_float4(accO[i][0] * inv, accO[i][1] * inv,
                           accO[i][2] * inv, accO[i][3] * inv);
    *(float4*)(Out + base + (size_t)(s0 + s) * HD_ + (tx << 2)) = o;
  }
}

// ---------------- add + l2-normalize (one wave per row) ----------------
__global__ __launch_bounds__(256) void addnorm_kernel(
    const float* __restrict__ X, const float* __restrict__ MH,
    float* __restrict__ XN) {
  int row = blockIdx.x * 4 + (threadIdx.x >> 6);
  int lane = threadIdx.x & 63;
  size_t off = (size_t)row * E_;
  float4 a0 = *(const float4*)(X + off + lane * 4);
  float4 m0 = *(const float4*)(MH + off + lane * 4);
  float4 a1 = *(const float4*)(X + off + 256 + lane * 4);
  float4 m1 = *(const float4*)(MH + off + 256 + lane * 4);
  float v0[4] = {a0.x + m0.x, a0.y + m0.y, a0.z + m0.z, a0.w + m0.w};
  float v1[4] = {a1.x + m1.x, a1.y + m1.y, a1.z + m1.z, a1.w + m1.w};
  float ss = 0.f;
#pragma unroll
  for (int j = 0; j < 4; ++j) ss += v0[j] * v0[j] + v1[j] * v1[j];
#pragma unroll
  for (int o = 32; o >= 1; o >>= 1) ss += __shfl_down(ss, o);
  ss = __shfl(ss, 0);
  float inv = rsqrtf(fmaxf(ss, 1e-12f));
  *(float4*)(XN + off + lane * 4) =
      make_float4(v0[0] * inv, v0[1] * inv, v0[2] * inv, v0[3] * inv);
  *(float4*)(XN + off + 256 + lane * 4) =
      make_float4(v1[0] * inv, v1[1] * inv, v1[2] * inv, v1[3] * inv);
}

// ---------------- conv-pool + dense + softmax head (one block per batch) ----
__global__ __launch_bounds__(256) void head_kernel(
    const float* __restrict__ X, const float* __restrict__ Wc,
    const float* __restrict__ bc, const float* __restrict__ Wd,
    const float* __restrict__ bd, float* __restrict__ out) {
  __shared__ float wc[5 * E_];
  __shared__ float pooled[LOUT_];
  __shared__ float red[256];
  __shared__ float lg[O_];
  int b = blockIdx.x, tid = threadIdx.x;
  for (int i = tid; i < 5 * E_; i += 256) wc[i] = Wc[i];
  __syncthreads();
  const float* xb = X + (size_t)b * S_ * E_;
  for (int l = 0; l < LOUT_; ++l) {
    // rows l*5 .. l*5+4 are 2560 contiguous floats; Wc flat [kw][e] matches.
    const float* xr = xb + (size_t)l * 5 * E_;
    float v = 0.f;
    for (int i = tid; i < 5 * E_; i += 256) v += xr[i] * wc[i];
    red[tid] = v;
    __syncthreads();
    for (int s2 = 128; s2 > 0; s2 >>= 1) {
      if (tid < s2) red[tid] += red[tid + s2];
      __syncthreads();
    }
    if (tid == 0) pooled[l] = red[0] + bc[0];
    __syncthreads();
  }
  for (int o = tid; o < O_; o += 256) {
    float acc = bd[o];
    for (int l = 0; l < LOUT_; ++l) acc += pooled[l] * Wd[l * O_ + o];
    lg[o] = acc;
  }
  __syncthreads();
  float mx = -1e30f;
  for (int o = tid; o < O_; o += 256) mx = fmaxf(mx, lg[o]);
  red[tid] = mx;
  __syncthreads();
  for (int s2 = 128; s2 > 0; s2 >>= 1) {
    if (tid < s2) red[tid] = fmaxf(red[tid], red[tid + s2]);
    __syncthreads();
  }
  mx = red[0];
  __syncthreads();
  float se = 0.f;
  for (int o = tid; o < O_; o += 256) {
    float e = expf(lg[o] - mx);
    lg[o] = e;
    se += e;
  }
  red[tid] = se;
  __syncthreads();
  for (int s2 = 128; s2 > 0; s2 >>= 1) {
    if (tid < s2) red[tid] += red[tid + s2];
    __syncthreads();
  }
  float inv = 1.f / red[0];
  for (int o = tid; o < O_; o += 256) out[(size_t)b * O_ + o] = lg[o] * inv;
}

extern "C" void kernel_launch(void* const* d_in, const int* in_sizes, int n_in,
                              void* d_out, int out_size, void* d_ws, size_t ws_size,
                              hipStream_t stream) {
  const int* tokens = (const int*)d_in[0];
  const float* emb = (const float*)d_in[1];
  const float* Wq = (const float*)d_in[2];
  const float* bq = (const float*)d_in[3];
  const float* Wk = (const float*)d_in[4];
  const float* bk = (const float*)d_in[5];
  const float* Wv = (const float*)d_in[6];
  const float* bv = (const float*)d_in[7];
  const float* Wo = (const float*)d_in[8];
  const float* bo = (const float*)d_in[9];
  const float* W1 = (const float*)d_in[10];
  const float* b1 = (const float*)d_in[11];
  const float* W2 = (const float*)d_in[12];
  const float* b2 = (const float*)d_in[13];
  const float* Wc = (const float*)d_in[14];
  const float* bc = (const float*)d_in[15];
  const float* Wd = (const float*)d_in[16];
  const float* bd = (const float*)d_in[17];
  float* out = (float*)d_out;

  // workspace: 4 regions of BS*E floats = 268.4 MB total
  //  r0 = X (activations), r1 = Q -> heads(in-place) -> FF1(lo),
  //  r2 = K -> MH -> FF1(hi), r3 = V -> XN
  size_t R = (size_t)BS_ * E_;
  float* X = (float*)d_ws;
  float* Qb = X + R;
  float* Kb = X + 2 * R;
  float* Vb = X + 3 * R;

  embed_kernel<<<dim3(BS_ * E_ / 4 / 256), dim3(256), 0, stream>>>(tokens, emb, X);

  dim3 g512(BS_ / 64, 512 / 64);
  dim3 g1024(BS_ / 64, 1024 / 64);
  dim3 blk(256);
  for (int i = 0; i < L_; ++i) {
    const float* Wqi = Wq + (size_t)i * H_ * E_ * D_;
    const float* Wki = Wk + (size_t)i * H_ * E_ * D_;
    const float* Wvi = Wv + (size_t)i * H_ * E_ * D_;
    gemm_kernel<1, 0, 0><<<g512, blk, 0, stream>>>(X, Wqi, bq + i * HD_, nullptr,
                                                   Qb, BS_, HD_, E_);
    gemm_kernel<1, 0, 0><<<g512, blk, 0, stream>>>(X, Wki, bk + i * HD_, nullptr,
                                                   Kb, BS_, HD_, E_);
    gemm_kernel<1, 0, 0><<<g512, blk, 0, stream>>>(X, Wvi, bv + i * HD_, nullptr,
                                                   Vb, BS_, HD_, E_);
    attn_kernel<<<dim3(B_ * H_ * (S_ / 64)), blk, 0, stream>>>(Qb, Kb, Vb, Qb);
    gemm_kernel<0, 0, 0><<<g512, blk, 0, stream>>>(
        Qb, Wo + (size_t)i * HD_ * E_, bo + i * E_, nullptr, Kb, BS_, E_, HD_);
    addnorm_kernel<<<dim3(BS_ / 4), blk, 0, stream>>>(X, Kb, Vb);
    gemm_kernel<0, 1, 0><<<g1024, blk, 0, stream>>>(
        Vb, W1 + (size_t)i * E_ * 2 * E_, b1 + (size_t)i * 2 * E_, nullptr, Qb,
        BS_, 2 * E_, E_);
    gemm_kernel<0, 0, 1><<<g512, blk, 0, stream>>>(
        Qb, W2 + (size_t)i * 2 * E_ * E_, b2 + (size_t)i * E_, Vb, X, BS_, E_,
        2 * E_);
  }
  head_kernel<<<dim3(B_), blk, 0, stream>>>(X, Wc, bc, Wd, bd, out);
}

// Round 2
// 2317.560 us; speedup vs baseline: 5.0783x; 5.0783x over previous
//
#include <hip/hip_runtime.h>
#include <cstddef>

constexpr int B_ = 64, S_ = 512, E_ = 512, H_ = 8, D_ = 64, L_ = 4, O_ = 1000;
constexpr int BS_ = B_ * S_;        // 32768
constexpr int HD_ = H_ * D_;        // 512
constexpr int LOUT_ = 102;
constexpr float SCALE_ = 0.04419417382415922f;  // 1/sqrt(512)

typedef __bf16 bf16x8 __attribute__((ext_vector_type(8)));
typedef __bf16 bf16x4 __attribute__((ext_vector_type(4)));
typedef __bf16 bf16x2 __attribute__((ext_vector_type(2)));
typedef float floatx4 __attribute__((ext_vector_type(4)));

__device__ inline void load16_lds(const __bf16* g, __bf16* l) {
  __builtin_amdgcn_global_load_lds(
      (const __attribute__((address_space(1))) void*)g,
      (__attribute__((address_space(3))) void*)l, 16, 0, 0);
}

// ---------------- weight transpose + bf16 convert ----------------
// in: fp32 [R][C] (z-slice at z*IZ). out: bf16 [C][R] at (z>>3)*OZL + (z&7)*OZH.
__global__ __launch_bounds__(256) void transpose_bf16(
    const float* __restrict__ in, __bf16* __restrict__ out,
    int R, int C, int IZ, int OZL, int OZH) {
  __shared__ float t[32][33];
  int z = blockIdx.z;
  const float* inz = in + (size_t)z * IZ;
  __bf16* outz = out + (size_t)(z >> 3) * OZL + (size_t)(z & 7) * OZH;
  int c0 = blockIdx.x * 32, r0 = blockIdx.y * 32;
  int x = threadIdx.x, y = threadIdx.y;  // (32,8)
#pragma unroll
  for (int j = 0; j < 32; j += 8) t[y + j][x] = inz[(size_t)(r0 + y + j) * C + c0 + x];
  __syncthreads();
#pragma unroll
  for (int j = 0; j < 32; j += 8)
    outz[(size_t)(c0 + y + j) * R + r0 + x] = (__bf16)t[x][y + j];
}

// ---------------- embedding + mask -> X fp32 + Ab bf16 ----------------
__global__ __launch_bounds__(256) void embed_kernel(
    const int* __restrict__ tokens, const float* __restrict__ emb,
    float* __restrict__ X, __bf16* __restrict__ Ab) {
  int idx = blockIdx.x * 256 + threadIdx.x;  // float4 index
  int bs = idx >> 7;
  int e = (idx & 127) << 2;
  int tok = tokens[bs];
  float4 v;
  if (tok == 0) v = make_float4(0.f, 0.f, 0.f, 0.f);
  else v = *(const float4*)(emb + (size_t)tok * E_ + e);
  size_t off = (size_t)bs * E_ + e;
  *(float4*)(X + off) = v;
  bf16x4 b;
  b[0] = (__bf16)v.x; b[1] = (__bf16)v.y; b[2] = (__bf16)v.z; b[3] = (__bf16)v.w;
  *(bf16x4*)(Ab + off) = b;
}

// ---------------- bf16 MFMA GEMM (m97-style, BK=64, xor-swizzled LDS) ------
// C[M,N] = act(A[M,K] @ B + bias (+ Rsd)).  Bt is [N][K] (B transposed).
// LDS chunk layout: chunk ci=(row*8+c) holds global (row, q=c^(row&7)) 8-elem kchunk.
template <int RELU, int RES, int OUTF, int OUTB>
__global__ __launch_bounds__(256) void gemm_bf16(
    const __bf16* __restrict__ A, const __bf16* __restrict__ Bt,
    const float* __restrict__ bias, const float* __restrict__ Rsd,
    float* __restrict__ Cf, __bf16* __restrict__ Cb, int N, int K) {
  __shared__ __align__(16) __bf16 As[128 * 64];
  __shared__ __align__(16) __bf16 Bs[128 * 64];
  int tid = threadIdx.x;
  int lane = tid & 63, w = tid >> 6;
  int m0 = blockIdx.x * 128, n0 = blockIdx.y * 128;
  int q4 = lane >> 4, a_ = lane & 15;
  floatx4 acc[4][4];
#pragma unroll
  for (int i = 0; i < 4; ++i)
#pragma unroll
    for (int j = 0; j < 4; ++j) acc[i][j] = (floatx4)(0.0f);

  for (int k0 = 0; k0 < K; k0 += 64) {
#pragma unroll
    for (int j = 0; j < 4; ++j) {
      int ci = (j * 4 + w) * 64 + lane;
      int row = ci >> 3, c = ci & 7, q = c ^ (row & 7);
      load16_lds(A + (size_t)(m0 + row) * K + k0 + q * 8, As + (size_t)(j * 4 + w) * 512);
    }
#pragma unroll
    for (int j = 0; j < 4; ++j) {
      int ci = (j * 4 + w) * 64 + lane;
      int row = ci >> 3, c = ci & 7, q = c ^ (row & 7);
      load16_lds(Bt + (size_t)(n0 + row) * K + k0 + q * 8, Bs + (size_t)(j * 4 + w) * 512);
    }
    __syncthreads();
#pragma unroll
    for (int ks = 0; ks < 2; ++ks) {
      bf16x8 af[4], bfr[4];
#pragma unroll
      for (int i = 0; i < 4; ++i) {
        int row = (w & 1) * 64 + i * 16 + a_;
        int q = ks * 4 + q4;
        af[i] = *(const bf16x8*)&As[(row * 8 + (q ^ (row & 7))) * 8];
      }
#pragma unroll
      for (int jc = 0; jc < 4; ++jc) {
        int row = (w >> 1) * 64 + jc * 16 + a_;
        int q = ks * 4 + q4;
        bfr[jc] = *(const bf16x8*)&Bs[(row * 8 + (q ^ (row & 7))) * 8];
      }
#pragma unroll
      for (int i = 0; i < 4; ++i)
#pragma unroll
        for (int jc = 0; jc < 4; ++jc)
          acc[i][jc] = __builtin_amdgcn_mfma_f32_16x16x32_bf16(af[i], bfr[jc],
                                                               acc[i][jc], 0, 0, 0);
    }
    __syncthreads();
  }
  // epilogue: C row = m0+(w&1)*64+i*16+q4*4+r, col = n0+(w>>1)*64+jc*16+a_
#pragma unroll
  for (int jc = 0; jc < 4; ++jc) {
    int n = n0 + (w >> 1) * 64 + jc * 16 + a_;
    float bv = bias[n];
#pragma unroll
    for (int i = 0; i < 4; ++i) {
      int rowb = m0 + (w & 1) * 64 + i * 16 + q4 * 4;
#pragma unroll
      for (int r = 0; r < 4; ++r) {
        float v = acc[i][jc][r] + bv;
        size_t off = (size_t)(rowb + r) * N + n;
        if (RES) v += Rsd[off];
        if (RELU) v = fmaxf(v, 0.f);
        if (OUTF) Cf[off] = v;
        if (OUTB) Cb[off] = (__bf16)v;
      }
    }
  }
}

// ---------------- MFMA flash attention (bf16) ----------------
// block = (b, h, 64-row Q tile); 4 waves, wave w owns S-rows [16w,16w+16).
__global__ __launch_bounds__(256) void attn_bf16(
    const __bf16* __restrict__ Q, const __bf16* __restrict__ Kg,
    const __bf16* __restrict__ Vg, __bf16* __restrict__ Out) {
  __shared__ __align__(16) __bf16 Qs[64 * 72];
  __shared__ __align__(16) __bf16 Ks[64 * 72];
  __shared__ __align__(16) __bf16 Vt[64 * 72];
  __shared__ __align__(16) __bf16 Ps[64 * 72];
  int tid = threadIdx.x, lane = tid & 63, w = tid >> 6;
  int q4 = lane >> 4, a_ = lane & 15;
  int s0 = blockIdx.x * 64, h = blockIdx.y, b = blockIdx.z;
  size_t rowbase = (size_t)b * S_ * HD_ + h * 64;
  // stage Q tile [64 s][64 d]
#pragma unroll
  for (int j = 0; j < 2; ++j) {
    int ci = j * 256 + tid;
    int row = ci >> 3, c = ci & 7;
    *(bf16x8*)&Qs[row * 72 + c * 8] =
        *(const bf16x8*)(Q + rowbase + (size_t)(s0 + row) * HD_ + c * 8);
  }
  float mrow[4], lrow[4];
#pragma unroll
  for (int r = 0; r < 4; ++r) { mrow[r] = -3.0e38f; lrow[r] = 0.f; }
  floatx4 accO[4];
#pragma unroll
  for (int j = 0; j < 4; ++j) accO[j] = (floatx4)(0.0f);

  for (int t0 = 0; t0 < S_; t0 += 64) {
    // stage K tile [64 t][64 d]
#pragma unroll
    for (int j = 0; j < 2; ++j) {
      int ci = j * 256 + tid;
      int row = ci >> 3, c = ci & 7;
      *(bf16x8*)&Ks[row * 72 + c * 8] =
          *(const bf16x8*)(Kg + rowbase + (size_t)(t0 + row) * HD_ + c * 8);
    }
    // stage V transposed -> Vt[64 d][64 t]
    {
      int tp = tid & 31, dg = tid >> 5;  // t pair, d-group of 8
      const __bf16* vp0 = Vg + rowbase + (size_t)(t0 + 2 * tp) * HD_ + dg * 8;
      const __bf16* vp1 = vp0 + HD_;
      bf16x8 v0 = *(const bf16x8*)vp0;
      bf16x8 v1 = *(const bf16x8*)vp1;
#pragma unroll
      for (int x = 0; x < 8; ++x) {
        bf16x2 p; p[0] = v0[x]; p[1] = v1[x];
        *(bf16x2*)&Vt[(dg * 8 + x) * 72 + 2 * tp] = p;
      }
    }
    __syncthreads();
    // S = Q K^T
    floatx4 sc[4];
#pragma unroll
    for (int jc = 0; jc < 4; ++jc) sc[jc] = (floatx4)(0.0f);
#pragma unroll
    for (int ks = 0; ks < 2; ++ks) {
      bf16x8 aq = *(const bf16x8*)&Qs[(16 * w + a_) * 72 + ks * 32 + q4 * 8];
#pragma unroll
      for (int jc = 0; jc < 4; ++jc) {
        bf16x8 bk = *(const bf16x8*)&Ks[(jc * 16 + a_) * 72 + ks * 32 + q4 * 8];
        sc[jc] = __builtin_amdgcn_mfma_f32_16x16x32_bf16(aq, bk, sc[jc], 0, 0, 0);
      }
    }
#pragma unroll
    for (int jc = 0; jc < 4; ++jc) sc[jc] *= SCALE_;
    // online softmax; lane's rows rr = q4*4+r (replicated over the 16 a_ lanes)
#pragma unroll
    for (int r = 0; r < 4; ++r) {
      float mx = fmaxf(fmaxf(sc[0][r], sc[1][r]), fmaxf(sc[2][r], sc[3][r]));
#pragma unroll
      for (int o = 1; o < 16; o <<= 1) mx = fmaxf(mx, __shfl_xor(mx, o));
      float mnew = fmaxf(mrow[r], mx);
      float alpha = __expf(mrow[r] - mnew);
      mrow[r] = mnew;
      float psum = 0.f;
#pragma unroll
      for (int jc = 0; jc < 4; ++jc) {
        float p = __expf(sc[jc][r] - mnew);
        psum += p;
        Ps[(16 * w + q4 * 4 + r) * 72 + jc * 16 + a_] = (__bf16)p;
      }
#pragma unroll
      for (int o = 1; o < 16; o <<= 1) psum += __shfl_xor(psum, o);
      lrow[r] = lrow[r] * alpha + psum;
#pragma unroll
      for (int jc = 0; jc < 4; ++jc) accO[jc][r] *= alpha;
    }
    // O += P V   (Ps wave-private rows; same-wave LDS RAW handled by lgkmcnt)
#pragma unroll
    for (int ks = 0; ks < 2; ++ks) {
      bf16x8 ap = *(const bf16x8*)&Ps[(16 * w + a_) * 72 + ks * 32 + q4 * 8];
#pragma unroll
      for (int jc = 0; jc < 4; ++jc) {
        bf16x8 bv = *(const bf16x8*)&Vt[(jc * 16 + a_) * 72 + ks * 32 + q4 * 8];
        accO[jc] = __builtin_amdgcn_mfma_f32_16x16x32_bf16(ap, bv, accO[jc], 0, 0, 0);
      }
    }
    __syncthreads();
  }
  // write heads (bf16), row = s0+16w+q4*4+r, col = jc*16+a_
#pragma unroll
  for (int r = 0; r < 4; ++r) {
    float inv = 1.f / lrow[r];
    int row = s0 + 16 * w + q4 * 4 + r;
#pragma unroll
    for (int jc = 0; jc < 4; ++jc)
      Out[rowbase + (size_t)row * HD_ + jc * 16 + a_] = (__bf16)(accO[jc][r] * inv);
  }
}

// ---------------- add + l2norm: X = l2norm(X + MH), Ab = bf16(X) ----------
__global__ __launch_bounds__(256) void addnorm_kernel(
    float* __restrict__ X, const __bf16* __restrict__ MH, __bf16* __restrict__ Ab) {
  int row = blockIdx.x * 4 + (threadIdx.x >> 6);
  int ln = threadIdx.x & 63;
  size_t off = (size_t)row * E_ + ln * 8;
  float xv[8];
  *(float4*)&xv[0] = *(const float4*)(X + off);
  *(float4*)&xv[4] = *(const float4*)(X + off + 4);
  bf16x8 mh = *(const bf16x8*)(MH + off);
  float ss = 0.f;
#pragma unroll
  for (int j = 0; j < 8; ++j) {
    xv[j] += (float)mh[j];
    ss += xv[j] * xv[j];
  }
#pragma unroll
  for (int o = 1; o < 64; o <<= 1) ss += __shfl_xor(ss, o);
  float inv = rsqrtf(fmaxf(ss, 1e-12f));
  bf16x8 ob;
#pragma unroll
  for (int j = 0; j < 8; ++j) {
    xv[j] *= inv;
    ob[j] = (__bf16)xv[j];
  }
  *(float4*)(X + off) = *(float4*)&xv[0];
  *(float4*)(X + off + 4) = *(float4*)&xv[4];
  *(bf16x8*)(Ab + off) = ob;
}

// ---------------- conv-pool + dense + softmax head ----------------
__global__ __launch_bounds__(256) void head_kernel(
    const float* __restrict__ X, const float* __restrict__ Wc,
    const float* __restrict__ bc, const float* __restrict__ Wd,
    const float* __restrict__ bd, float* __restrict__ out) {
  __shared__ float wc[5 * E_];
  __shared__ float pooled[LOUT_];
  __shared__ float red[256];
  __shared__ float lg[O_];
  int b = blockIdx.x, tid = threadIdx.x;
  int wv = tid >> 6, ln = tid & 63;
  for (int i = tid; i < 5 * E_; i += 256) wc[i] = Wc[i];
  __syncthreads();
  const float* xb = X + (size_t)b * S_ * E_;
  float bc0 = bc[0];
  for (int l = wv; l < LOUT_; l += 4) {
    const float* xr = xb + (size_t)l * 5 * E_;
    float v = 0.f;
    for (int i = ln; i < 5 * E_; i += 64) v += xr[i] * wc[i];
#pragma unroll
    for (int o = 32; o >= 1; o >>= 1) v += __shfl_down(v, o);
    if (ln == 0) pooled[l] = v + bc0;
  }
  __syncthreads();
  for (int o = tid; o < O_; o += 256) {
    float acc = bd[o];
    for (int l = 0; l < LOUT_; ++l) acc += pooled[l] * Wd[l * O_ + o];
    lg[o] = acc;
  }
  __syncthreads();
  float mx = -3.0e38f;
  for (int o = tid; o < O_; o += 256) mx = fmaxf(mx, lg[o]);
  red[tid] = mx;
  __syncthreads();
  for (int s2 = 128; s2 > 0; s2 >>= 1) {
    if (tid < s2) red[tid] = fmaxf(red[tid], red[tid + s2]);
    __syncthreads();
  }
  mx = red[0];
  __syncthreads();
  float se = 0.f;
  for (int o = tid; o < O_; o += 256) {
    float e = __expf(lg[o] - mx);
    lg[o] = e;
    se += e;
  }
  red[tid] = se;
  __syncthreads();
  for (int s2 = 128; s2 > 0; s2 >>= 1) {
    if (tid < s2) red[tid] += red[tid + s2];
    __syncthreads();
  }
  float inv = 1.f / red[0];
  for (int o = tid; o < O_; o += 256) out[(size_t)b * O_ + o] = lg[o] * inv;
}

extern "C" void kernel_launch(void* const* d_in, const int* in_sizes, int n_in,
                              void* d_out, int out_size, void* d_ws, size_t ws_size,
                              hipStream_t stream) {
  const int* tokens = (const int*)d_in[0];
  const float* emb = (const float*)d_in[1];
  const float* Wq = (const float*)d_in[2];
  const float* bq = (const float*)d_in[3];
  const float* Wk = (const float*)d_in[4];
  const float* bk = (const float*)d_in[5];
  const float* Wv = (const float*)d_in[6];
  const float* bv = (const float*)d_in[7];
  const float* Wo = (const float*)d_in[8];
  const float* bo = (const float*)d_in[9];
  const float* W1 = (const float*)d_in[10];
  const float* b1 = (const float*)d_in[11];
  const float* W2 = (const float*)d_in[12];
  const float* b2 = (const float*)d_in[13];
  const float* Wc = (const float*)d_in[14];
  const float* bc = (const float*)d_in[15];
  const float* Wd = (const float*)d_in[16];
  const float* bd = (const float*)d_in[17];
  float* out = (float*)d_out;

  // ws layout (bytes): X f32 [0,64M) | Ab bf16 [64M,96M) | Q [96M,128M)
  //                    | K [128M,160M) | V [160M,192M) | Wt [192M,208M)
  char* ws = (char*)d_ws;
  float* X = (float*)ws;
  __bf16* Ab = (__bf16*)(ws + 67108864);
  __bf16* Qb = (__bf16*)(ws + 100663296);
  __bf16* Kb = (__bf16*)(ws + 134217728);
  __bf16* Vb = (__bf16*)(ws + 167772160);
  __bf16* Wt = (__bf16*)(ws + 201326592);
  __bf16* Wt_q = Wt;
  __bf16* Wt_k = Wt + 1048576;
  __bf16* Wt_v = Wt + 2097152;
  __bf16* Wt_o = Wt + 3145728;
  __bf16* Wt_1 = Wt + 4194304;
  __bf16* Wt_2 = Wt + 6291456;

  dim3 tb(32, 8);
  transpose_bf16<<<dim3(2, 16, 32), tb, 0, stream>>>(Wq, Wt_q, 512, 64, 32768, 262144, 32768);
  transpose_bf16<<<dim3(2, 16, 32), tb, 0, stream>>>(Wk, Wt_k, 512, 64, 32768, 262144, 32768);
  transpose_bf16<<<dim3(2, 16, 32), tb, 0, stream>>>(Wv, Wt_v, 512, 64, 32768, 262144, 32768);
  transpose_bf16<<<dim3(16, 16, 4), tb, 0, stream>>>(Wo, Wt_o, 512, 512, 262144, 0, 262144);
  transpose_bf16<<<dim3(32, 16, 4), tb, 0, stream>>>(W1, Wt_1, 512, 1024, 524288, 0, 524288);
  transpose_bf16<<<dim3(16, 32, 4), tb, 0, stream>>>(W2, Wt_2, 1024, 512, 524288, 0, 524288);

  embed_kernel<<<dim3(BS_ * E_ / 4 / 256), dim3(256), 0, stream>>>(tokens, emb, X, Ab);

  dim3 blk(256);
  dim3 g512(256, 4), g1024(256, 8);
  for (int i = 0; i < L_; ++i) {
    gemm_bf16<0, 0, 0, 1><<<g512, blk, 0, stream>>>(
        Ab, Wt_q + (size_t)i * 262144, bq + i * HD_, nullptr, nullptr, Qb, 512, 512);
    gemm_bf16<0, 0, 0, 1><<<g512, blk, 0, stream>>>(
        Ab, Wt_k + (size_t)i * 262144, bk + i * HD_, nullptr, nullptr, Kb, 512, 512);
    gemm_bf16<0, 0, 0, 1><<<g512, blk, 0, stream>>>(
        Ab, Wt_v + (size_t)i * 262144, bv + i * HD_, nullptr, nullptr, Vb, 512, 512);
    attn_bf16<<<dim3(8, 8, 64), blk, 0, stream>>>(Qb, Kb, Vb, Qb);
    gemm_bf16<0, 0, 0, 1><<<g512, blk, 0, stream>>>(
        Qb, Wt_o + (size_t)i * 262144, bo + i * E_, nullptr, nullptr, Kb, 512, 512);
    addnorm_kernel<<<dim3(BS_ / 4), blk, 0, stream>>>(X, Kb, Ab);
    gemm_bf16<1, 0, 0, 1><<<g1024, blk, 0, stream>>>(
        Ab, Wt_1 + (size_t)i * 524288, b1 + (size_t)i * 2 * E_, nullptr, nullptr,
        Kb, 1024, 512);
    gemm_bf16<0, 1, 1, 1><<<g512, blk, 0, stream>>>(
        Kb, Wt_2 + (size_t)i * 524288, b2 + (size_t)i * E_, X, X, Ab, 512, 1024);
  }
  head_kernel<<<dim3(B_), blk, 0, stream>>>(X, Wc, bc, Wd, bd, out);
}

// Round 3
// 2141.956 us; speedup vs baseline: 5.4946x; 1.0820x over previous
//
#include <hip/hip_runtime.h>
#include <cstddef>

constexpr int B_ = 64, S_ = 512, E_ = 512, H_ = 8, D_ = 64, L_ = 4, O_ = 1000;
constexpr int BS_ = B_ * S_;        // 32768
constexpr int HD_ = H_ * D_;        // 512
constexpr int QS_ = 1536;           // fused QKV row stride
constexpr int LOUT_ = 102;
constexpr float SCALE_ = 0.04419417382415922f;  // 1/sqrt(512)

typedef __bf16 bf16x8 __attribute__((ext_vector_type(8)));
typedef __bf16 bf16x4 __attribute__((ext_vector_type(4)));
typedef __bf16 bf16x2 __attribute__((ext_vector_type(2)));
typedef float floatx4 __attribute__((ext_vector_type(4)));

__device__ inline void load16_lds(const __bf16* g, __bf16* l) {
  __builtin_amdgcn_global_load_lds(
      (const __attribute__((address_space(1))) void*)g,
      (__attribute__((address_space(3))) void*)l, 16, 0, 0);
}

// ---------------- weight transpose + bf16 convert ----------------
// in: fp32 [R][C] (z-slice at z*IZ). out: bf16 [C][R] at (z>>3)*OZL + (z&7)*OZH.
__global__ __launch_bounds__(256) void transpose_bf16(
    const float* __restrict__ in, __bf16* __restrict__ out,
    int R, int C, int IZ, int OZL, int OZH) {
  __shared__ float t[32][33];
  int z = blockIdx.z;
  const float* inz = in + (size_t)z * IZ;
  __bf16* outz = out + (size_t)(z >> 3) * OZL + (size_t)(z & 7) * OZH;
  int c0 = blockIdx.x * 32, r0 = blockIdx.y * 32;
  int x = threadIdx.x, y = threadIdx.y;  // (32,8)
#pragma unroll
  for (int j = 0; j < 32; j += 8) t[y + j][x] = inz[(size_t)(r0 + y + j) * C + c0 + x];
  __syncthreads();
#pragma unroll
  for (int j = 0; j < 32; j += 8)
    outz[(size_t)(c0 + y + j) * R + r0 + x] = (__bf16)t[x][y + j];
}

// ---------------- concat qkv bias: [L][1536] = bq|bk|bv ----------------
__global__ __launch_bounds__(256) void bias_concat(
    const float* __restrict__ bq, const float* __restrict__ bk,
    const float* __restrict__ bv, float* __restrict__ qkvb) {
  int idx = blockIdx.x * 256 + threadIdx.x;  // < 6144
  int l = idx / QS_, j = idx % QS_;
  float v;
  if (j < 512) v = bq[l * 512 + j];
  else if (j < 1024) v = bk[l * 512 + j - 512];
  else v = bv[l * 512 + j - 1024];
  qkvb[idx] = v;
}

// ---------------- embedding + mask -> X fp32 + Ab bf16 ----------------
__global__ __launch_bounds__(256) void embed_kernel(
    const int* __restrict__ tokens, const float* __restrict__ emb,
    float* __restrict__ X, __bf16* __restrict__ Ab) {
  int idx = blockIdx.x * 256 + threadIdx.x;  // float4 index
  int bs = idx >> 7;
  int e = (idx & 127) << 2;
  int tok = tokens[bs];
  float4 v;
  if (tok == 0) v = make_float4(0.f, 0.f, 0.f, 0.f);
  else v = *(const float4*)(emb + (size_t)tok * E_ + e);
  size_t off = (size_t)bs * E_ + e;
  *(float4*)(X + off) = v;
  bf16x4 b;
  b[0] = (__bf16)v.x; b[1] = (__bf16)v.y; b[2] = (__bf16)v.z; b[3] = (__bf16)v.w;
  *(bf16x4*)(Ab + off) = b;
}

// ---------------- bf16 MFMA GEMM (m97-style, BK=64, xor-swizzled LDS) ------
// C[M,N] = act(A[M,K] @ B + bias (+ Rsd)).  Bt is [N][K] (B transposed).
// A row stride = lda. C row stride = N.
template <int RELU, int RES, int OUTF, int OUTB>
__global__ __launch_bounds__(256) void gemm_bf16(
    const __bf16* __restrict__ A, const __bf16* __restrict__ Bt,
    const float* __restrict__ bias, const float* __restrict__ Rsd,
    float* __restrict__ Cf, __bf16* __restrict__ Cb, int N, int K, int lda) {
  __shared__ __align__(16) __bf16 As[128 * 64];
  __shared__ __align__(16) __bf16 Bs[128 * 64];
  int tid = threadIdx.x;
  int lane = tid & 63, w = tid >> 6;
  int m0 = blockIdx.x * 128, n0 = blockIdx.y * 128;
  int q4 = lane >> 4, a_ = lane & 15;
  floatx4 acc[4][4];
#pragma unroll
  for (int i = 0; i < 4; ++i)
#pragma unroll
    for (int j = 0; j < 4; ++j) acc[i][j] = (floatx4)(0.0f);

  for (int k0 = 0; k0 < K; k0 += 64) {
#pragma unroll
    for (int j = 0; j < 4; ++j) {
      int ci = (j * 4 + w) * 64 + lane;
      int row = ci >> 3, c = ci & 7, q = c ^ (row & 7);
      load16_lds(A + (size_t)(m0 + row) * lda + k0 + q * 8, As + (size_t)(j * 4 + w) * 512);
    }
#pragma unroll
    for (int j = 0; j < 4; ++j) {
      int ci = (j * 4 + w) * 64 + lane;
      int row = ci >> 3, c = ci & 7, q = c ^ (row & 7);
      load16_lds(Bt + (size_t)(n0 + row) * K + k0 + q * 8, Bs + (size_t)(j * 4 + w) * 512);
    }
    __syncthreads();
#pragma unroll
    for (int ks = 0; ks < 2; ++ks) {
      bf16x8 af[4], bfr[4];
#pragma unroll
      for (int i = 0; i < 4; ++i) {
        int row = (w & 1) * 64 + i * 16 + a_;
        int q = ks * 4 + q4;
        af[i] = *(const bf16x8*)&As[(row * 8 + (q ^ (row & 7))) * 8];
      }
#pragma unroll
      for (int jc = 0; jc < 4; ++jc) {
        int row = (w >> 1) * 64 + jc * 16 + a_;
        int q = ks * 4 + q4;
        bfr[jc] = *(const bf16x8*)&Bs[(row * 8 + (q ^ (row & 7))) * 8];
      }
#pragma unroll
      for (int i = 0; i < 4; ++i)
#pragma unroll
        for (int jc = 0; jc < 4; ++jc)
          acc[i][jc] = __builtin_amdgcn_mfma_f32_16x16x32_bf16(af[i], bfr[jc],
                                                               acc[i][jc], 0, 0, 0);
    }
    __syncthreads();
  }
  // epilogue: C row = m0+(w&1)*64+i*16+q4*4+r, col = n0+(w>>1)*64+jc*16+a_
#pragma unroll
  for (int jc = 0; jc < 4; ++jc) {
    int n = n0 + (w >> 1) * 64 + jc * 16 + a_;
    float bv = bias[n];
#pragma unroll
    for (int i = 0; i < 4; ++i) {
      int rowb = m0 + (w & 1) * 64 + i * 16 + q4 * 4;
#pragma unroll
      for (int r = 0; r < 4; ++r) {
        float v = acc[i][jc][r] + bv;
        size_t off = (size_t)(rowb + r) * N + n;
        if (RES) v += Rsd[off];
        if (RELU) v = fmaxf(v, 0.f);
        if (OUTF) Cf[off] = v;
        if (OUTB) Cb[off] = (__bf16)v;
      }
    }
  }
}

// ---------------- MFMA flash attention (bf16, strided QKV rows) -----------
// block = (b, h, 64-row Q tile); 4 waves, wave w owns S-rows [16w,16w+16).
// Q/K/V at col offsets {0,512,1024}+h*64 within rows of stride QS_=1536.
// Heads written in-place over the Q slice (block reads its Q tile first; no
// other block touches this (b,h,s-tile) Q slice).
__global__ __launch_bounds__(256) void attn_bf16(
    __bf16* __restrict__ QKV) {
  __shared__ __align__(16) __bf16 Qs[64 * 72];
  __shared__ __align__(16) __bf16 Ks[64 * 72];
  __shared__ __align__(16) __bf16 Vt[64 * 72];
  __shared__ __align__(16) __bf16 Ps[64 * 72];
  int tid = threadIdx.x, lane = tid & 63, w = tid >> 6;
  int q4 = lane >> 4, a_ = lane & 15;
  int s0 = blockIdx.x * 64, h = blockIdx.y, b = blockIdx.z;
  size_t rowbase = (size_t)b * S_ * QS_ + h * 64;
  const __bf16* Qg = QKV + rowbase;
  const __bf16* Kg = QKV + rowbase + 512;
  const __bf16* Vg = QKV + rowbase + 1024;
  // stage Q tile [64 s][64 d]
#pragma unroll
  for (int j = 0; j < 2; ++j) {
    int ci = j * 256 + tid;
    int row = ci >> 3, c = ci & 7;
    *(bf16x8*)&Qs[row * 72 + c * 8] =
        *(const bf16x8*)(Qg + (size_t)(s0 + row) * QS_ + c * 8);
  }
  float mrow[4], lrow[4];
#pragma unroll
  for (int r = 0; r < 4; ++r) { mrow[r] = -3.0e38f; lrow[r] = 0.f; }
  floatx4 accO[4];
#pragma unroll
  for (int j = 0; j < 4; ++j) accO[j] = (floatx4)(0.0f);

  for (int t0 = 0; t0 < S_; t0 += 64) {
    // stage K tile [64 t][64 d]
#pragma unroll
    for (int j = 0; j < 2; ++j) {
      int ci = j * 256 + tid;
      int row = ci >> 3, c = ci & 7;
      *(bf16x8*)&Ks[row * 72 + c * 8] =
          *(const bf16x8*)(Kg + (size_t)(t0 + row) * QS_ + c * 8);
    }
    // stage V transposed -> Vt[64 d][64 t]
    {
      int tp = tid & 31, dg = tid >> 5;  // t pair, d-group of 8
      const __bf16* vp0 = Vg + (size_t)(t0 + 2 * tp) * QS_ + dg * 8;
      const __bf16* vp1 = vp0 + QS_;
      bf16x8 v0 = *(const bf16x8*)vp0;
      bf16x8 v1 = *(const bf16x8*)vp1;
#pragma unroll
      for (int x = 0; x < 8; ++x) {
        bf16x2 p; p[0] = v0[x]; p[1] = v1[x];
        *(bf16x2*)&Vt[(dg * 8 + x) * 72 + 2 * tp] = p;
      }
    }
    __syncthreads();
    // S = Q K^T
    floatx4 sc[4];
#pragma unroll
    for (int jc = 0; jc < 4; ++jc) sc[jc] = (floatx4)(0.0f);
#pragma unroll
    for (int ks = 0; ks < 2; ++ks) {
      bf16x8 aq = *(const bf16x8*)&Qs[(16 * w + a_) * 72 + ks * 32 + q4 * 8];
#pragma unroll
      for (int jc = 0; jc < 4; ++jc) {
        bf16x8 bk = *(const bf16x8*)&Ks[(jc * 16 + a_) * 72 + ks * 32 + q4 * 8];
        sc[jc] = __builtin_amdgcn_mfma_f32_16x16x32_bf16(aq, bk, sc[jc], 0, 0, 0);
      }
    }
#pragma unroll
    for (int jc = 0; jc < 4; ++jc) sc[jc] *= SCALE_;
    // online softmax; lane's rows rr = q4*4+r (replicated over the 16 a_ lanes)
#pragma unroll
    for (int r = 0; r < 4; ++r) {
      float mx = fmaxf(fmaxf(sc[0][r], sc[1][r]), fmaxf(sc[2][r], sc[3][r]));
#pragma unroll
      for (int o = 1; o < 16; o <<= 1) mx = fmaxf(mx, __shfl_xor(mx, o));
      float mnew = fmaxf(mrow[r], mx);
      float alpha = __expf(mrow[r] - mnew);
      mrow[r] = mnew;
      float psum = 0.f;
#pragma unroll
      for (int jc = 0; jc < 4; ++jc) {
        float p = __expf(sc[jc][r] - mnew);
        psum += p;
        Ps[(16 * w + q4 * 4 + r) * 72 + jc * 16 + a_] = (__bf16)p;
      }
#pragma unroll
      for (int o = 1; o < 16; o <<= 1) psum += __shfl_xor(psum, o);
      lrow[r] = lrow[r] * alpha + psum;
#pragma unroll
      for (int jc = 0; jc < 4; ++jc) accO[jc][r] *= alpha;
    }
    // O += P V   (Ps wave-private rows; same-wave LDS RAW handled by lgkmcnt)
#pragma unroll
    for (int ks = 0; ks < 2; ++ks) {
      bf16x8 ap = *(const bf16x8*)&Ps[(16 * w + a_) * 72 + ks * 32 + q4 * 8];
#pragma unroll
      for (int jc = 0; jc < 4; ++jc) {
        bf16x8 bv = *(const bf16x8*)&Vt[(jc * 16 + a_) * 72 + ks * 32 + q4 * 8];
        accO[jc] = __builtin_amdgcn_mfma_f32_16x16x32_bf16(ap, bv, accO[jc], 0, 0, 0);
      }
    }
    __syncthreads();
  }
  // write heads (bf16) into Q slice: row = s0+16w+q4*4+r, col = jc*16+a_
#pragma unroll
  for (int r = 0; r < 4; ++r) {
    float inv = 1.f / lrow[r];
    int row = s0 + 16 * w + q4 * 4 + r;
#pragma unroll
    for (int jc = 0; jc < 4; ++jc)
      QKV[rowbase + (size_t)row * QS_ + jc * 16 + a_] = (__bf16)(accO[jc][r] * inv);
  }
}

// ---------------- add + l2norm: X = l2norm(X + MH), Ab = bf16(X) ----------
__global__ __launch_bounds__(256) void addnorm_kernel(
    float* __restrict__ X, const __bf16* __restrict__ MH, __bf16* __restrict__ Ab) {
  int row = blockIdx.x * 4 + (threadIdx.x >> 6);
  int ln = threadIdx.x & 63;
  size_t off = (size_t)row * E_ + ln * 8;
  float xv[8];
  *(float4*)&xv[0] = *(const float4*)(X + off);
  *(float4*)&xv[4] = *(const float4*)(X + off + 4);
  bf16x8 mh = *(const bf16x8*)(MH + off);
  float ss = 0.f;
#pragma unroll
  for (int j = 0; j < 8; ++j) {
    xv[j] += (float)mh[j];
    ss += xv[j] * xv[j];
  }
#pragma unroll
  for (int o = 1; o < 64; o <<= 1) ss += __shfl_xor(ss, o);
  float inv = rsqrtf(fmaxf(ss, 1e-12f));
  bf16x8 ob;
#pragma unroll
  for (int j = 0; j < 8; ++j) {
    xv[j] *= inv;
    ob[j] = (__bf16)xv[j];
  }
  *(float4*)(X + off) = *(float4*)&xv[0];
  *(float4*)(X + off + 4) = *(float4*)&xv[4];
  *(bf16x8*)(Ab + off) = ob;
}

// ---------------- conv-pool: pooled[b][l] = dot(X[b, 5l:5l+5, :], Wc)+bc ---
// one wave per (b,l) pair; 6528 waves = 1632 blocks.
__global__ __launch_bounds__(256) void conv_pool_kernel(
    const float* __restrict__ X, const float* __restrict__ Wc,
    const float* __restrict__ bc, float* __restrict__ pooled) {
  int wid = blockIdx.x * 4 + (threadIdx.x >> 6);
  int ln = threadIdx.x & 63;
  int b = wid / LOUT_, l = wid % LOUT_;
  const float* xr = X + (size_t)b * S_ * E_ + (size_t)l * 5 * E_;
  float v = 0.f;
#pragma unroll
  for (int j = 0; j < 10; ++j) {
    int i = (j * 64 + ln) * 4;
    float4 x4 = *(const float4*)(xr + i);
    float4 w4 = *(const float4*)(Wc + i);
    v += x4.x * w4.x + x4.y * w4.y + x4.z * w4.z + x4.w * w4.w;
  }
#pragma unroll
  for (int o = 32; o >= 1; o >>= 1) v += __shfl_down(v, o);
  if (ln == 0) pooled[b * LOUT_ + l] = v + bc[0];
}

// ---------------- dense + softmax: out[b] = softmax(pooled[b] @ Wd + bd) ---
__global__ __launch_bounds__(256) void dense_softmax_kernel(
    const float* __restrict__ pooled, const float* __restrict__ Wd,
    const float* __restrict__ bd, float* __restrict__ out) {
  __shared__ float pl[LOUT_];
  __shared__ float red[256];
  __shared__ float lg[O_];
  int b = blockIdx.x, tid = threadIdx.x;
  if (tid < LOUT_) pl[tid] = pooled[b * LOUT_ + tid];
  __syncthreads();
  for (int o = tid; o < O_; o += 256) {
    float acc = bd[o];
#pragma unroll 6
    for (int l = 0; l < LOUT_; ++l) acc += pl[l] * Wd[l * O_ + o];
    lg[o] = acc;
  }
  __syncthreads();
  float mx = -3.0e38f;
  for (int o = tid; o < O_; o += 256) mx = fmaxf(mx, lg[o]);
  red[tid] = mx;
  __syncthreads();
  for (int s2 = 128; s2 > 0; s2 >>= 1) {
    if (tid < s2) red[tid] = fmaxf(red[tid], red[tid + s2]);
    __syncthreads();
  }
  mx = red[0];
  __syncthreads();
  float se = 0.f;
  for (int o = tid; o < O_; o += 256) {
    float e = __expf(lg[o] - mx);
    lg[o] = e;
    se += e;
  }
  red[tid] = se;
  __syncthreads();
  for (int s2 = 128; s2 > 0; s2 >>= 1) {
    if (tid < s2) red[tid] += red[tid + s2];
    __syncthreads();
  }
  float inv = 1.f / red[0];
  for (int o = tid; o < O_; o += 256) out[(size_t)b * O_ + o] = lg[o] * inv;
}

extern "C" void kernel_launch(void* const* d_in, const int* in_sizes, int n_in,
                              void* d_out, int out_size, void* d_ws, size_t ws_size,
                              hipStream_t stream) {
  const int* tokens = (const int*)d_in[0];
  const float* emb = (const float*)d_in[1];
  const float* Wq = (const float*)d_in[2];
  const float* bq = (const float*)d_in[3];
  const float* Wk = (const float*)d_in[4];
  const float* bk = (const float*)d_in[5];
  const float* Wv = (const float*)d_in[6];
  const float* bv = (const float*)d_in[7];
  const float* Wo = (const float*)d_in[8];
  const float* bo = (const float*)d_in[9];
  const float* W1 = (const float*)d_in[10];
  const float* b1 = (const float*)d_in[11];
  const float* W2 = (const float*)d_in[12];
  const float* b2 = (const float*)d_in[13];
  const float* Wc = (const float*)d_in[14];
  const float* bc = (const float*)d_in[15];
  const float* Wd = (const float*)d_in[16];
  const float* bd = (const float*)d_in[17];
  float* out = (float*)d_out;

  // ws layout (bytes):
  //  X f32        [0,   64M)
  //  Ab bf16      [64M, 96M)
  //  QKVb bf16    [96M, 192M)   [32768][1536]; FF1 out reuses [96M,160M)
  //  MH bf16      [192M,224M)   [32768][512]
  //  Wt bf16      [224M,240M)   qkv 6M | Wo 2M | W1 4M | W2 4M
  //  qkvbias f32  [240M, +24K)
  //  pooled f32   [..., +26.2K)
  char* ws = (char*)d_ws;
  float* X = (float*)ws;
  __bf16* Ab = (__bf16*)(ws + 67108864);
  __bf16* QKVb = (__bf16*)(ws + 100663296);
  __bf16* FF1b = QKVb;  // reuse (QKV dead after Wo gemm)
  __bf16* MHb = (__bf16*)(ws + 201326592);
  __bf16* Wt = (__bf16*)(ws + 234881024);
  __bf16* Wt_qkv = Wt;                 // [L][1536][512] : 3,145,728 elems
  __bf16* Wt_o = Wt + 3145728;         // [L][512][512]
  __bf16* Wt_1 = Wt + 4194304;         // [L][1024][512]
  __bf16* Wt_2 = Wt + 6291456;         // [L][512][1024]
  float* qkvbias = (float*)(ws + 251658240);
  float* pooled = qkvbias + 6144;

  dim3 tb(32, 8);
  // Wq/Wk/Wv: [L,H,512,64] (z=l*8+h) -> Wt_qkv[L][{q|k|v} 512 rows][512]
  transpose_bf16<<<dim3(2, 16, 32), tb, 0, stream>>>(Wq, Wt_qkv + 0,      512, 64, 32768, 786432, 32768);
  transpose_bf16<<<dim3(2, 16, 32), tb, 0, stream>>>(Wk, Wt_qkv + 262144, 512, 64, 32768, 786432, 32768);
  transpose_bf16<<<dim3(2, 16, 32), tb, 0, stream>>>(Wv, Wt_qkv + 524288, 512, 64, 32768, 786432, 32768);
  transpose_bf16<<<dim3(16, 16, 4), tb, 0, stream>>>(Wo, Wt_o, 512, 512, 262144, 0, 262144);
  transpose_bf16<<<dim3(32, 16, 4), tb, 0, stream>>>(W1, Wt_1, 512, 1024, 524288, 0, 524288);
  transpose_bf16<<<dim3(16, 32, 4), tb, 0, stream>>>(W2, Wt_2, 1024, 512, 524288, 0, 524288);
  bias_concat<<<dim3(24), dim3(256), 0, stream>>>(bq, bk, bv, qkvbias);

  embed_kernel<<<dim3(BS_ * E_ / 4 / 256), dim3(256), 0, stream>>>(tokens, emb, X, Ab);

  dim3 blk(256);
  dim3 gqkv(256, 12), g512(256, 4), g1024(256, 8);
  for (int i = 0; i < L_; ++i) {
    gemm_bf16<0, 0, 0, 1><<<gqkv, blk, 0, stream>>>(
        Ab, Wt_qkv + (size_t)i * 786432, qkvbias + i * QS_, nullptr, nullptr,
        QKVb, QS_, 512, 512);
    attn_bf16<<<dim3(8, 8, 64), blk, 0, stream>>>(QKVb);
    gemm_bf16<0, 0, 0, 1><<<g512, blk, 0, stream>>>(
        QKVb, Wt_o + (size_t)i * 262144, bo + i * E_, nullptr, nullptr, MHb,
        512, 512, QS_);
    addnorm_kernel<<<dim3(BS_ / 4), blk, 0, stream>>>(X, MHb, Ab);
    gemm_bf16<1, 0, 0, 1><<<g1024, blk, 0, stream>>>(
        Ab, Wt_1 + (size_t)i * 524288, b1 + (size_t)i * 2 * E_, nullptr, nullptr,
        FF1b, 1024, 512, 512);
    gemm_bf16<0, 1, 1, 1><<<g512, blk, 0, stream>>>(
        FF1b, Wt_2 + (size_t)i * 524288, b2 + (size_t)i * E_, X, X, Ab,
        512, 1024, 1024);
  }
  conv_pool_kernel<<<dim3(BS_ * LOUT_ / S_ / 4), blk, 0, stream>>>(X, Wc, bc, pooled);
  dense_softmax_kernel<<<dim3(B_), blk, 0, stream>>>(pooled, Wd, bd, out);
}

// Round 4
// 1887.732 us; speedup vs baseline: 6.2345x; 1.1347x over previous
//
#include <hip/hip_runtime.h>
#include <cstddef>

constexpr int B_ = 64, S_ = 512, E_ = 512, H_ = 8, D_ = 64, L_ = 4, O_ = 1000;
constexpr int BS_ = B_ * S_;        // 32768
constexpr int HD_ = H_ * D_;        // 512
constexpr int QS_ = 1536;           // fused QKV row stride
constexpr int LOUT_ = 102;
constexpr float SCALE_ = 0.04419417382415922f;  // 1/sqrt(512)

typedef __bf16 bf16x8 __attribute__((ext_vector_type(8)));
typedef __bf16 bf16x4 __attribute__((ext_vector_type(4)));
typedef __bf16 bf16x2 __attribute__((ext_vector_type(2)));
typedef float floatx4 __attribute__((ext_vector_type(4)));

__device__ inline void load16_lds(const __bf16* g, __bf16* l) {
  __builtin_amdgcn_global_load_lds(
      (const __attribute__((address_space(1))) void*)g,
      (__attribute__((address_space(3))) void*)l, 16, 0, 0);
}

// ---------------- weight transpose + bf16 convert ----------------
// in: fp32 [R][C] (z-slice at z*IZ). out: bf16 [C][R] at (z>>3)*OZL + (z&7)*OZH.
__global__ __launch_bounds__(256) void transpose_bf16(
    const float* __restrict__ in, __bf16* __restrict__ out,
    int R, int C, int IZ, int OZL, int OZH) {
  __shared__ float t[32][33];
  int z = blockIdx.z;
  const float* inz = in + (size_t)z * IZ;
  __bf16* outz = out + (size_t)(z >> 3) * OZL + (size_t)(z & 7) * OZH;
  int c0 = blockIdx.x * 32, r0 = blockIdx.y * 32;
  int x = threadIdx.x, y = threadIdx.y;  // (32,8)
#pragma unroll
  for (int j = 0; j < 32; j += 8) t[y + j][x] = inz[(size_t)(r0 + y + j) * C + c0 + x];
  __syncthreads();
#pragma unroll
  for (int j = 0; j < 32; j += 8)
    outz[(size_t)(c0 + y + j) * R + r0 + x] = (__bf16)t[x][y + j];
}

// ---------------- concat qkv bias: [L][1536] = bq|bk|bv ----------------
__global__ __launch_bounds__(256) void bias_concat(
    const float* __restrict__ bq, const float* __restrict__ bk,
    const float* __restrict__ bv, float* __restrict__ qkvb) {
  int idx = blockIdx.x * 256 + threadIdx.x;  // < 6144
  int l = idx / QS_, j = idx % QS_;
  float v;
  if (j < 512) v = bq[l * 512 + j];
  else if (j < 1024) v = bk[l * 512 + j - 512];
  else v = bv[l * 512 + j - 1024];
  qkvb[idx] = v;
}

// ---------------- embedding + mask -> X fp32 + Ab bf16 ----------------
__global__ __launch_bounds__(256) void embed_kernel(
    const int* __restrict__ tokens, const float* __restrict__ emb,
    float* __restrict__ X, __bf16* __restrict__ Ab) {
  int idx = blockIdx.x * 256 + threadIdx.x;  // float4 index
  int bs = idx >> 7;
  int e = (idx & 127) << 2;
  int tok = tokens[bs];
  float4 v;
  if (tok == 0) v = make_float4(0.f, 0.f, 0.f, 0.f);
  else v = *(const float4*)(emb + (size_t)tok * E_ + e);
  size_t off = (size_t)bs * E_ + e;
  *(float4*)(X + off) = v;
  bf16x4 b;
  b[0] = (__bf16)v.x; b[1] = (__bf16)v.y; b[2] = (__bf16)v.z; b[3] = (__bf16)v.w;
  *(bf16x4*)(Ab + off) = b;
}

// ---------------- bf16 MFMA GEMM (m97-style, BK=64, xor-swizzled LDS) ------
// C[M,N] = act(A[M,K] @ B + bias (+ Rsd)).  Bt is [N][K] (B transposed).
// A row stride = lda. C row stride = N.  SCQ: scale cols<512 by SCALE_ (QKV).
template <int RELU, int RES, int OUTF, int OUTB, int SCQ>
__global__ __launch_bounds__(256) void gemm_bf16(
    const __bf16* __restrict__ A, const __bf16* __restrict__ Bt,
    const float* __restrict__ bias, const float* __restrict__ Rsd,
    float* __restrict__ Cf, __bf16* __restrict__ Cb, int N, int K, int lda) {
  __shared__ __align__(16) __bf16 As[128 * 64];
  __shared__ __align__(16) __bf16 Bs[128 * 64];
  int tid = threadIdx.x;
  int lane = tid & 63, w = tid >> 6;
  int m0 = blockIdx.x * 128, n0 = blockIdx.y * 128;
  int q4 = lane >> 4, a_ = lane & 15;
  floatx4 acc[4][4];
#pragma unroll
  for (int i = 0; i < 4; ++i)
#pragma unroll
    for (int j = 0; j < 4; ++j) acc[i][j] = (floatx4)(0.0f);

  for (int k0 = 0; k0 < K; k0 += 64) {
#pragma unroll
    for (int j = 0; j < 4; ++j) {
      int ci = (j * 4 + w) * 64 + lane;
      int row = ci >> 3, c = ci & 7, q = c ^ (row & 7);
      load16_lds(A + (size_t)(m0 + row) * lda + k0 + q * 8, As + (size_t)(j * 4 + w) * 512);
    }
#pragma unroll
    for (int j = 0; j < 4; ++j) {
      int ci = (j * 4 + w) * 64 + lane;
      int row = ci >> 3, c = ci & 7, q = c ^ (row & 7);
      load16_lds(Bt + (size_t)(n0 + row) * K + k0 + q * 8, Bs + (size_t)(j * 4 + w) * 512);
    }
    __syncthreads();
#pragma unroll
    for (int ks = 0; ks < 2; ++ks) {
      bf16x8 af[4], bfr[4];
#pragma unroll
      for (int i = 0; i < 4; ++i) {
        int row = (w & 1) * 64 + i * 16 + a_;
        int q = ks * 4 + q4;
        af[i] = *(const bf16x8*)&As[(row * 8 + (q ^ (row & 7))) * 8];
      }
#pragma unroll
      for (int jc = 0; jc < 4; ++jc) {
        int row = (w >> 1) * 64 + jc * 16 + a_;
        int q = ks * 4 + q4;
        bfr[jc] = *(const bf16x8*)&Bs[(row * 8 + (q ^ (row & 7))) * 8];
      }
#pragma unroll
      for (int i = 0; i < 4; ++i)
#pragma unroll
        for (int jc = 0; jc < 4; ++jc)
          acc[i][jc] = __builtin_amdgcn_mfma_f32_16x16x32_bf16(af[i], bfr[jc],
                                                               acc[i][jc], 0, 0, 0);
    }
    __syncthreads();
  }
  // epilogue: C row = m0+(w&1)*64+i*16+q4*4+r, col = n0+(w>>1)*64+jc*16+a_
#pragma unroll
  for (int jc = 0; jc < 4; ++jc) {
    int n = n0 + (w >> 1) * 64 + jc * 16 + a_;
    float bv = bias[n];
#pragma unroll
    for (int i = 0; i < 4; ++i) {
      int rowb = m0 + (w & 1) * 64 + i * 16 + q4 * 4;
#pragma unroll
      for (int r = 0; r < 4; ++r) {
        float v = acc[i][jc][r] + bv;
        if (SCQ) { if (n < 512) v *= SCALE_; }
        size_t off = (size_t)(rowb + r) * N + n;
        if (RES) v += Rsd[off];
        if (RELU) v = fmaxf(v, 0.f);
        if (OUTF) Cf[off] = v;
        if (OUTB) Cb[off] = (__bf16)v;
      }
    }
  }
}

// ---------------- MFMA flash attention v2 (S^T layout, swizzled LDS) ------
// block = (b, h, 256-row Q slab); 4 waves; wave w owns s-chunks (cc*4+w)*16.
// Q pre-scaled by 1/sqrt(E) in QKV gemm epilogue. Heads written in-place
// over the Q slice (only this block touches its (b,h,s-slab) Q slice).
__global__ __launch_bounds__(256, 2) void attn_bf16(__bf16* __restrict__ QKV) {
  __shared__ __align__(16) __bf16 Qs[256 * 64];  // swizzled chunks
  __shared__ __align__(16) __bf16 Ks[64 * 64];   // swizzled
  __shared__ __align__(16) __bf16 Vt[64 * 64];   // V^T [d][t], swizzled
  __shared__ __align__(16) __bf16 Ps[64 * 64];   // P [s][t], swizzled
  int tid = threadIdx.x, lane = tid & 63, w = tid >> 6;
  int q4 = lane >> 4, a_ = lane & 15;
  int s0 = blockIdx.x * 256, h = blockIdx.y, b = blockIdx.z;
  size_t rowbase = (size_t)b * S_ * QS_ + h * 64;
  __bf16* Qg = QKV + rowbase;
  const __bf16* Kg = QKV + rowbase + 512;
  const __bf16* Vg = QKV + rowbase + 1024;
  // stage Q slab (256 rows), swizzled
#pragma unroll
  for (int j = 0; j < 8; ++j) {
    int ci = j * 256 + w * 64 + lane;
    int row = ci >> 3, c = ci & 7, q = c ^ (row & 7);
    load16_lds(Qg + (size_t)(s0 + row) * QS_ + q * 8, Qs + (j * 256 + w * 64) * 8);
  }
  float mrow[4], lrow[4];
  floatx4 accO[4][4];
#pragma unroll
  for (int cc = 0; cc < 4; ++cc) {
    mrow[cc] = -3.0e38f; lrow[cc] = 0.f;
#pragma unroll
    for (int jc = 0; jc < 4; ++jc) accO[cc][jc] = (floatx4)(0.0f);
  }

  for (int t0 = 0; t0 < S_; t0 += 64) {
    // stage K tile, swizzled
#pragma unroll
    for (int j = 0; j < 2; ++j) {
      int ci = j * 256 + w * 64 + lane;
      int row = ci >> 3, c = ci & 7, q = c ^ (row & 7);
      load16_lds(Kg + (size_t)(t0 + row) * QS_ + q * 8, Ks + (j * 256 + w * 64) * 8);
    }
    // stage V transposed -> Vt[d][t], swizzled chunks
    {
      int tp = tid & 31, dg = tid >> 5;
      bf16x8 v0 = *(const bf16x8*)(Vg + (size_t)(t0 + 2 * tp) * QS_ + dg * 8);
      bf16x8 v1 = *(const bf16x8*)(Vg + (size_t)(t0 + 2 * tp + 1) * QS_ + dg * 8);
#pragma unroll
      for (int x = 0; x < 8; ++x) {
        int d = dg * 8 + x;
        bf16x2 p; p[0] = v0[x]; p[1] = v1[x];
        *(bf16x2*)&Vt[(d * 8 + ((tp >> 2) ^ (d & 7))) * 8 + (tp & 3) * 2] = p;
      }
    }
    __syncthreads();
    // K and V^T fragments (shared across the 4 s-chunks)
    bf16x8 af[2][4], bv[2][4];
#pragma unroll
    for (int ks = 0; ks < 2; ++ks)
#pragma unroll
      for (int jc = 0; jc < 4; ++jc) {
        int row = jc * 16 + a_, q = ks * 4 + q4;
        af[ks][jc] = *(const bf16x8*)&Ks[(row * 8 + (q ^ (row & 7))) * 8];
        bv[ks][jc] = *(const bf16x8*)&Vt[(row * 8 + (q ^ (row & 7))) * 8];
      }
#pragma unroll
    for (int cc = 0; cc < 4; ++cc) {
      int sbase = (cc * 4 + w) * 16;
      // S^T = K Q^T : rows t = jc*16+q4*4+r, col s = sbase + a_
      floatx4 sc[4];
#pragma unroll
      for (int jc = 0; jc < 4; ++jc) sc[jc] = (floatx4)(0.0f);
#pragma unroll
      for (int ks = 0; ks < 2; ++ks) {
        int row = sbase + a_, q = ks * 4 + q4;
        bf16x8 bq = *(const bf16x8*)&Qs[(row * 8 + (q ^ (row & 7))) * 8];
#pragma unroll
        for (int jc = 0; jc < 4; ++jc)
          sc[jc] = __builtin_amdgcn_mfma_f32_16x16x32_bf16(af[ks][jc], bq,
                                                           sc[jc], 0, 0, 0);
      }
      // online softmax: per lane, all 16 values share column s = sbase+a_
      float mx = sc[0][0];
#pragma unroll
      for (int jc = 0; jc < 4; ++jc)
#pragma unroll
        for (int r = 0; r < 4; ++r) mx = fmaxf(mx, sc[jc][r]);
      mx = fmaxf(mx, __shfl_xor(mx, 16));
      mx = fmaxf(mx, __shfl_xor(mx, 32));
      float mnew = fmaxf(mrow[cc], mx);
      float alpha = __expf(mrow[cc] - mnew);
      mrow[cc] = mnew;
      float ps = 0.f;
      int prow = w * 16 + a_;
#pragma unroll
      for (int jc = 0; jc < 4; ++jc) {
        bf16x4 pb;
#pragma unroll
        for (int r = 0; r < 4; ++r) {
          float p = __expf(sc[jc][r] - mnew);
          ps += p;
          pb[r] = (__bf16)p;
        }
        int pc = jc * 2 + (q4 >> 1);
        *(bf16x4*)&Ps[(prow * 8 + (pc ^ (prow & 7))) * 8 + (q4 & 1) * 4] = pb;
      }
      ps += __shfl_xor(ps, 16);
      ps += __shfl_xor(ps, 32);
      lrow[cc] = lrow[cc] * alpha + ps;
      float aal[4];
#pragma unroll
      for (int r = 0; r < 4; ++r) aal[r] = __shfl(alpha, q4 * 4 + r);
#pragma unroll
      for (int jc = 0; jc < 4; ++jc) {
        floatx4 t = accO[cc][jc];
#pragma unroll
        for (int r = 0; r < 4; ++r) t[r] *= aal[r];
        accO[cc][jc] = t;
      }
      // O += P V  (Ps rows wave-private; same-wave RAW ordered via lgkmcnt)
#pragma unroll
      for (int ks = 0; ks < 2; ++ks) {
        int q = ks * 4 + q4;
        bf16x8 ap = *(const bf16x8*)&Ps[(prow * 8 + (q ^ (prow & 7))) * 8];
#pragma unroll
        for (int jc = 0; jc < 4; ++jc)
          accO[cc][jc] = __builtin_amdgcn_mfma_f32_16x16x32_bf16(
              ap, bv[ks][jc], accO[cc][jc], 0, 0, 0);
      }
    }
    __syncthreads();
  }
  // epilogue: row = s0+(cc*4+w)*16+q4*4+r, col = jc*16+a_  (into Q slice)
#pragma unroll
  for (int cc = 0; cc < 4; ++cc) {
    float inv = 1.f / lrow[cc];
    float linv[4];
#pragma unroll
    for (int r = 0; r < 4; ++r) linv[r] = __shfl(inv, q4 * 4 + r);
    int srow = s0 + (cc * 4 + w) * 16 + q4 * 4;
#pragma unroll
    for (int r = 0; r < 4; ++r)
#pragma unroll
      for (int jc = 0; jc < 4; ++jc)
        Qg[(size_t)(srow + r) * QS_ + jc * 16 + a_] =
            (__bf16)(accO[cc][jc][r] * linv[r]);
  }
}

// ---------------- add + l2norm: X = l2norm(X + MH), Ab = bf16(X) ----------
__global__ __launch_bounds__(256) void addnorm_kernel(
    float* __restrict__ X, const __bf16* __restrict__ MH, __bf16* __restrict__ Ab) {
  int row = blockIdx.x * 4 + (threadIdx.x >> 6);
  int ln = threadIdx.x & 63;
  size_t off = (size_t)row * E_ + ln * 8;
  float xv[8];
  *(float4*)&xv[0] = *(const float4*)(X + off);
  *(float4*)&xv[4] = *(const float4*)(X + off + 4);
  bf16x8 mh = *(const bf16x8*)(MH + off);
  float ss = 0.f;
#pragma unroll
  for (int j = 0; j < 8; ++j) {
    xv[j] += (float)mh[j];
    ss += xv[j] * xv[j];
  }
#pragma unroll
  for (int o = 1; o < 64; o <<= 1) ss += __shfl_xor(ss, o);
  float inv = rsqrtf(fmaxf(ss, 1e-12f));
  bf16x8 ob;
#pragma unroll
  for (int j = 0; j < 8; ++j) {
    xv[j] *= inv;
    ob[j] = (__bf16)xv[j];
  }
  *(float4*)(X + off) = *(float4*)&xv[0];
  *(float4*)(X + off + 4) = *(float4*)&xv[4];
  *(bf16x8*)(Ab + off) = ob;
}

// ---------------- conv-pool: pooled[b][l] = dot(X[b, 5l:5l+5, :], Wc)+bc ---
__global__ __launch_bounds__(256) void conv_pool_kernel(
    const float* __restrict__ X, const float* __restrict__ Wc,
    const float* __restrict__ bc, float* __restrict__ pooled) {
  int wid = blockIdx.x * 4 + (threadIdx.x >> 6);
  int ln = threadIdx.x & 63;
  int b = wid / LOUT_, l = wid % LOUT_;
  const float* xr = X + (size_t)b * S_ * E_ + (size_t)l * 5 * E_;
  float v = 0.f;
#pragma unroll
  for (int j = 0; j < 10; ++j) {
    int i = (j * 64 + ln) * 4;
    float4 x4 = *(const float4*)(xr + i);
    float4 w4 = *(const float4*)(Wc + i);
    v += x4.x * w4.x + x4.y * w4.y + x4.z * w4.z + x4.w * w4.w;
  }
#pragma unroll
  for (int o = 32; o >= 1; o >>= 1) v += __shfl_down(v, o);
  if (ln == 0) pooled[b * LOUT_ + l] = v + bc[0];
}

// ---------------- dense + softmax: out[b] = softmax(pooled[b] @ Wd + bd) ---
__global__ __launch_bounds__(256) void dense_softmax_kernel(
    const float* __restrict__ pooled, const float* __restrict__ Wd,
    const float* __restrict__ bd, float* __restrict__ out) {
  __shared__ float pl[LOUT_];
  __shared__ float red[256];
  __shared__ float lg[O_];
  int b = blockIdx.x, tid = threadIdx.x;
  if (tid < LOUT_) pl[tid] = pooled[b * LOUT_ + tid];
  __syncthreads();
  for (int o = tid; o < O_; o += 256) {
    float acc = bd[o];
#pragma unroll 6
    for (int l = 0; l < LOUT_; ++l) acc += pl[l] * Wd[l * O_ + o];
    lg[o] = acc;
  }
  __syncthreads();
  float mx = -3.0e38f;
  for (int o = tid; o < O_; o += 256) mx = fmaxf(mx, lg[o]);
  red[tid] = mx;
  __syncthreads();
  for (int s2 = 128; s2 > 0; s2 >>= 1) {
    if (tid < s2) red[tid] = fmaxf(red[tid], red[tid + s2]);
    __syncthreads();
  }
  mx = red[0];
  __syncthreads();
  float se = 0.f;
  for (int o = tid; o < O_; o += 256) {
    float e = __expf(lg[o] - mx);
    lg[o] = e;
    se += e;
  }
  red[tid] = se;
  __syncthreads();
  for (int s2 = 128; s2 > 0; s2 >>= 1) {
    if (tid < s2) red[tid] += red[tid + s2];
    __syncthreads();
  }
  float inv = 1.f / red[0];
  for (int o = tid; o < O_; o += 256) out[(size_t)b * O_ + o] = lg[o] * inv;
}

extern "C" void kernel_launch(void* const* d_in, const int* in_sizes, int n_in,
                              void* d_out, int out_size, void* d_ws, size_t ws_size,
                              hipStream_t stream) {
  const int* tokens = (const int*)d_in[0];
  const float* emb = (const float*)d_in[1];
  const float* Wq = (const float*)d_in[2];
  const float* bq = (const float*)d_in[3];
  const float* Wk = (const float*)d_in[4];
  const float* bk = (const float*)d_in[5];
  const float* Wv = (const float*)d_in[6];
  const float* bv = (const float*)d_in[7];
  const float* Wo = (const float*)d_in[8];
  const float* bo = (const float*)d_in[9];
  const float* W1 = (const float*)d_in[10];
  const float* b1 = (const float*)d_in[11];
  const float* W2 = (const float*)d_in[12];
  const float* b2 = (const float*)d_in[13];
  const float* Wc = (const float*)d_in[14];
  const float* bc = (const float*)d_in[15];
  const float* Wd = (const float*)d_in[16];
  const float* bd = (const float*)d_in[17];
  float* out = (float*)d_out;

  // ws layout (bytes):
  //  X f32        [0,   64M)
  //  Ab bf16      [64M, 96M)
  //  QKVb bf16    [96M, 192M)   [32768][1536]; FF1 out reuses [96M,160M)
  //  MH bf16      [192M,224M)   [32768][512]
  //  Wt bf16      [224M,240M)   qkv 6M | Wo 2M | W1 4M | W2 4M
  //  qkvbias f32  [240M, +24K)
  //  pooled f32   [..., +26.2K)
  char* ws = (char*)d_ws;
  float* X = (float*)ws;
  __bf16* Ab = (__bf16*)(ws + 67108864);
  __bf16* QKVb = (__bf16*)(ws + 100663296);
  __bf16* FF1b = QKVb;  // reuse (QKV dead after Wo gemm)
  __bf16* MHb = (__bf16*)(ws + 201326592);
  __bf16* Wt = (__bf16*)(ws + 234881024);
  __bf16* Wt_qkv = Wt;                 // [L][1536][512]
  __bf16* Wt_o = Wt + 3145728;         // [L][512][512]
  __bf16* Wt_1 = Wt + 4194304;         // [L][1024][512]
  __bf16* Wt_2 = Wt + 6291456;         // [L][512][1024]
  float* qkvbias = (float*)(ws + 251658240);
  float* pooled = qkvbias + 6144;

  dim3 tb(32, 8);
  transpose_bf16<<<dim3(2, 16, 32), tb, 0, stream>>>(Wq, Wt_qkv + 0,      512, 64, 32768, 786432, 32768);
  transpose_bf16<<<dim3(2, 16, 32), tb, 0, stream>>>(Wk, Wt_qkv + 262144, 512, 64, 32768, 786432, 32768);
  transpose_bf16<<<dim3(2, 16, 32), tb, 0, stream>>>(Wv, Wt_qkv + 524288, 512, 64, 32768, 786432, 32768);
  transpose_bf16<<<dim3(16, 16, 4), tb, 0, stream>>>(Wo, Wt_o, 512, 512, 262144, 0, 262144);
  transpose_bf16<<<dim3(32, 16, 4), tb, 0, stream>>>(W1, Wt_1, 512, 1024, 524288, 0, 524288);
  transpose_bf16<<<dim3(16, 32, 4), tb, 0, stream>>>(W2, Wt_2, 1024, 512, 524288, 0, 524288);
  bias_concat<<<dim3(24), dim3(256), 0, stream>>>(bq, bk, bv, qkvbias);

  embed_kernel<<<dim3(BS_ * E_ / 4 / 256), dim3(256), 0, stream>>>(tokens, emb, X, Ab);

  dim3 blk(256);
  dim3 gqkv(256, 12), g512(256, 4), g1024(256, 8);
  for (int i = 0; i < L_; ++i) {
    gemm_bf16<0, 0, 0, 1, 1><<<gqkv, blk, 0, stream>>>(
        Ab, Wt_qkv + (size_t)i * 786432, qkvbias + i * QS_, nullptr, nullptr,
        QKVb, QS_, 512, 512);
    attn_bf16<<<dim3(2, 8, 64), blk, 0, stream>>>(QKVb);
    gemm_bf16<0, 0, 0, 1, 0><<<g512, blk, 0, stream>>>(
        QKVb, Wt_o + (size_t)i * 262144, bo + i * E_, nullptr, nullptr, MHb,
        512, 512, QS_);
    addnorm_kernel<<<dim3(BS_ / 4), blk, 0, stream>>>(X, MHb, Ab);
    gemm_bf16<1, 0, 0, 1, 0><<<g1024, blk, 0, stream>>>(
        Ab, Wt_1 + (size_t)i * 524288, b1 + (size_t)i * 2 * E_, nullptr, nullptr,
        FF1b, 1024, 512, 512);
    gemm_bf16<0, 1, 1, 1, 0><<<g512, blk, 0, stream>>>(
        FF1b, Wt_2 + (size_t)i * 524288, b2 + (size_t)i * E_, X, X, Ab,
        512, 1024, 1024);
  }
  conv_pool_kernel<<<dim3(BS_ * LOUT_ / S_ / 4), blk, 0, stream>>>(X, Wc, bc, pooled);
  dense_softmax_kernel<<<dim3(B_), blk, 0, stream>>>(pooled, Wd, bd, out);
}

// Round 5
// 1772.176 us; speedup vs baseline: 6.6411x; 1.0652x over previous
//
#include <hip/hip_runtime.h>
#include <cstddef>

constexpr int B_ = 64, S_ = 512, E_ = 512, H_ = 8, D_ = 64, L_ = 4, O_ = 1000;
constexpr int BS_ = B_ * S_;        // 32768
constexpr int HD_ = H_ * D_;        // 512
constexpr int QS_ = 1536;           // fused QKV row stride
constexpr int LOUT_ = 102;
constexpr float SCALE_ = 0.04419417382415922f;  // 1/sqrt(512)

typedef __bf16 bf16x8 __attribute__((ext_vector_type(8)));
typedef __bf16 bf16x4 __attribute__((ext_vector_type(4)));
typedef __bf16 bf16x2 __attribute__((ext_vector_type(2)));
typedef float floatx4 __attribute__((ext_vector_type(4)));

__device__ inline void load16_lds(const __bf16* g, __bf16* l) {
  __builtin_amdgcn_global_load_lds(
      (const __attribute__((address_space(1))) void*)g,
      (__attribute__((address_space(3))) void*)l, 16, 0, 0);
}

// ---------------- weight transpose + bf16 convert ----------------
// in: fp32 [R][C] (z-slice at z*IZ). out: bf16 [C][R] at (z>>3)*OZL + (z&7)*OZH.
__global__ __launch_bounds__(256) void transpose_bf16(
    const float* __restrict__ in, __bf16* __restrict__ out,
    int R, int C, int IZ, int OZL, int OZH) {
  __shared__ float t[32][33];
  int z = blockIdx.z;
  const float* inz = in + (size_t)z * IZ;
  __bf16* outz = out + (size_t)(z >> 3) * OZL + (size_t)(z & 7) * OZH;
  int c0 = blockIdx.x * 32, r0 = blockIdx.y * 32;
  int x = threadIdx.x, y = threadIdx.y;  // (32,8)
#pragma unroll
  for (int j = 0; j < 32; j += 8) t[y + j][x] = inz[(size_t)(r0 + y + j) * C + c0 + x];
  __syncthreads();
#pragma unroll
  for (int j = 0; j < 32; j += 8)
    outz[(size_t)(c0 + y + j) * R + r0 + x] = (__bf16)t[x][y + j];
}

// ---------------- concat qkv bias: [L][1536] = bq|bk|bv ----------------
__global__ __launch_bounds__(256) void bias_concat(
    const float* __restrict__ bq, const float* __restrict__ bk,
    const float* __restrict__ bv, float* __restrict__ qkvb) {
  int idx = blockIdx.x * 256 + threadIdx.x;  // < 6144
  int l = idx / QS_, j = idx % QS_;
  float v;
  if (j < 512) v = bq[l * 512 + j];
  else if (j < 1024) v = bk[l * 512 + j - 512];
  else v = bv[l * 512 + j - 1024];
  qkvb[idx] = v;
}

// ---------------- embedding + mask -> X fp32 + Ab bf16 ----------------
__global__ __launch_bounds__(256) void embed_kernel(
    const int* __restrict__ tokens, const float* __restrict__ emb,
    float* __restrict__ X, __bf16* __restrict__ Ab) {
  int idx = blockIdx.x * 256 + threadIdx.x;  // float4 index
  int bs = idx >> 7;
  int e = (idx & 127) << 2;
  int tok = tokens[bs];
  float4 v;
  if (tok == 0) v = make_float4(0.f, 0.f, 0.f, 0.f);
  else v = *(const float4*)(emb + (size_t)tok * E_ + e);
  size_t off = (size_t)bs * E_ + e;
  *(float4*)(X + off) = v;
  bf16x4 b;
  b[0] = (__bf16)v.x; b[1] = (__bf16)v.y; b[2] = (__bf16)v.z; b[3] = (__bf16)v.w;
  *(bf16x4*)(Ab + off) = b;
}

// ---------------- bf16 MFMA GEMM (m97-style, BK=64, xor-swizzled LDS) ------
// C[M,N] = act(A[M,K] @ B + bias (+ Rsd)).  Bt is [N][K] (B transposed).
// A row stride = lda. C row stride = N.  SCQ: scale cols<512 by SCALE_ (QKV).
// MFMA operands swapped (D holds C^T fragments): lane owns row m = a_,
// 4 consecutive cols n = jc*16 + q4*4 + r  -> vectorized epilogue.
// bf16 C staged through LDS (pad 136) -> 256B-contiguous coalesced stores.
template <int RELU, int RES, int OUTF, int OUTB, int SCQ>
__global__ __launch_bounds__(256) void gemm_bf16(
    const __bf16* __restrict__ A, const __bf16* __restrict__ Bt,
    const float* __restrict__ bias, const float* __restrict__ Rsd,
    float* __restrict__ Cf, __bf16* __restrict__ Cb, int N, int K, int lda) {
  __shared__ __align__(16) __bf16 smem[128 * 136];  // As | Bs overlay, then Cs
  __bf16* As = smem;
  __bf16* Bs = smem + 8192;
  int tid = threadIdx.x;
  int lane = tid & 63, w = tid >> 6;
  int m0 = blockIdx.x * 128, n0 = blockIdx.y * 128;
  int q4 = lane >> 4, a_ = lane & 15;
  floatx4 acc[4][4];
#pragma unroll
  for (int i = 0; i < 4; ++i)
#pragma unroll
    for (int j = 0; j < 4; ++j) acc[i][j] = (floatx4)(0.0f);

  for (int k0 = 0; k0 < K; k0 += 64) {
#pragma unroll
    for (int j = 0; j < 4; ++j) {
      int ci = (j * 4 + w) * 64 + lane;
      int row = ci >> 3, c = ci & 7, q = c ^ (row & 7);
      load16_lds(A + (size_t)(m0 + row) * lda + k0 + q * 8, As + (size_t)(j * 4 + w) * 512);
    }
#pragma unroll
    for (int j = 0; j < 4; ++j) {
      int ci = (j * 4 + w) * 64 + lane;
      int row = ci >> 3, c = ci & 7, q = c ^ (row & 7);
      load16_lds(Bt + (size_t)(n0 + row) * K + k0 + q * 8, Bs + (size_t)(j * 4 + w) * 512);
    }
    __syncthreads();
#pragma unroll
    for (int ks = 0; ks < 2; ++ks) {
      bf16x8 af[4], bfr[4];
#pragma unroll
      for (int i = 0; i < 4; ++i) {
        int row = (w & 1) * 64 + i * 16 + a_;
        int q = ks * 4 + q4;
        af[i] = *(const bf16x8*)&As[(row * 8 + (q ^ (row & 7))) * 8];
      }
#pragma unroll
      for (int jc = 0; jc < 4; ++jc) {
        int row = (w >> 1) * 64 + jc * 16 + a_;
        int q = ks * 4 + q4;
        bfr[jc] = *(const bf16x8*)&Bs[(row * 8 + (q ^ (row & 7))) * 8];
      }
      // swapped operands: acc[i][jc][r] = C[m0+(w&1)*64+i*16+a_][n0+(w>>1)*64+jc*16+q4*4+r]
#pragma unroll
      for (int i = 0; i < 4; ++i)
#pragma unroll
        for (int jc = 0; jc < 4; ++jc)
          acc[i][jc] = __builtin_amdgcn_mfma_f32_16x16x32_bf16(bfr[jc], af[i],
                                                               acc[i][jc], 0, 0, 0);
    }
    __syncthreads();
  }
  // ---- epilogue: vectorized, bf16 staged via LDS ----
#pragma unroll
  for (int i = 0; i < 4; ++i) {
    int ml = (w & 1) * 64 + i * 16 + a_;
    int m = m0 + ml;
#pragma unroll
    for (int jc = 0; jc < 4; ++jc) {
      int nl = (w >> 1) * 64 + jc * 16 + q4 * 4;
      int n = n0 + nl;
      float4 bi = *(const float4*)(bias + n);
      floatx4 v = acc[i][jc];
      v[0] += bi.x; v[1] += bi.y; v[2] += bi.z; v[3] += bi.w;
      if (SCQ) { if (n < 512) v *= SCALE_; }
      if (RES) {
        float4 rv = *(const float4*)(Rsd + (size_t)m * N + n);
        v[0] += rv.x; v[1] += rv.y; v[2] += rv.z; v[3] += rv.w;
      }
      if (RELU) {
#pragma unroll
        for (int r = 0; r < 4; ++r) v[r] = fmaxf(v[r], 0.f);
      }
      if (OUTF) {
        float4 o = make_float4(v[0], v[1], v[2], v[3]);
        *(float4*)(Cf + (size_t)m * N + n) = o;
      }
      if (OUTB) {
        bf16x4 ob;
#pragma unroll
        for (int r = 0; r < 4; ++r) ob[r] = (__bf16)v[r];
        *(bf16x4*)&smem[ml * 136 + nl] = ob;
      }
    }
  }
  if (OUTB) {
    __syncthreads();
#pragma unroll
    for (int it = 0; it < 8; ++it) {
      int cid = it * 256 + tid;
      int row = cid >> 4, c8 = cid & 15;
      bf16x8 val = *(const bf16x8*)&smem[row * 136 + c8 * 8];
      *(bf16x8*)(Cb + (size_t)(m0 + row) * N + n0 + c8 * 8) = val;
    }
  }
}

// ---------------- MFMA flash attention v2 (S^T layout, swizzled LDS) ------
// block = (b, h, 256-row Q slab); 4 waves; wave w owns s-chunks (cc*4+w)*16.
// Q pre-scaled by 1/sqrt(E) in QKV gemm epilogue. Heads written in-place
// over the Q slice (only this block touches its (b,h,s-slab) Q slice).
__global__ __launch_bounds__(256, 2) void attn_bf16(__bf16* __restrict__ QKV) {
  __shared__ __align__(16) __bf16 Qs[256 * 64];  // swizzled chunks
  __shared__ __align__(16) __bf16 Ks[64 * 64];   // swizzled
  __shared__ __align__(16) __bf16 Vt[64 * 64];   // V^T [d][t], swizzled
  __shared__ __align__(16) __bf16 Ps[64 * 64];   // P [s][t], swizzled
  int tid = threadIdx.x, lane = tid & 63, w = tid >> 6;
  int q4 = lane >> 4, a_ = lane & 15;
  int s0 = blockIdx.x * 256, h = blockIdx.y, b = blockIdx.z;
  size_t rowbase = (size_t)b * S_ * QS_ + h * 64;
  __bf16* Qg = QKV + rowbase;
  const __bf16* Kg = QKV + rowbase + 512;
  const __bf16* Vg = QKV + rowbase + 1024;
  // stage Q slab (256 rows), swizzled
#pragma unroll
  for (int j = 0; j < 8; ++j) {
    int ci = j * 256 + w * 64 + lane;
    int row = ci >> 3, c = ci & 7, q = c ^ (row & 7);
    load16_lds(Qg + (size_t)(s0 + row) * QS_ + q * 8, Qs + (j * 256 + w * 64) * 8);
  }
  float mrow[4], lrow[4];
  floatx4 accO[4][4];
#pragma unroll
  for (int cc = 0; cc < 4; ++cc) {
    mrow[cc] = -3.0e38f; lrow[cc] = 0.f;
#pragma unroll
    for (int jc = 0; jc < 4; ++jc) accO[cc][jc] = (floatx4)(0.0f);
  }

  for (int t0 = 0; t0 < S_; t0 += 64) {
    // stage K tile, swizzled
#pragma unroll
    for (int j = 0; j < 2; ++j) {
      int ci = j * 256 + w * 64 + lane;
      int row = ci >> 3, c = ci & 7, q = c ^ (row & 7);
      load16_lds(Kg + (size_t)(t0 + row) * QS_ + q * 8, Ks + (j * 256 + w * 64) * 8);
    }
    // stage V transposed -> Vt[d][t], swizzled chunks
    {
      int tp = tid & 31, dg = tid >> 5;
      bf16x8 v0 = *(const bf16x8*)(Vg + (size_t)(t0 + 2 * tp) * QS_ + dg * 8);
      bf16x8 v1 = *(const bf16x8*)(Vg + (size_t)(t0 + 2 * tp + 1) * QS_ + dg * 8);
#pragma unroll
      for (int x = 0; x < 8; ++x) {
        int d = dg * 8 + x;
        bf16x2 p; p[0] = v0[x]; p[1] = v1[x];
        *(bf16x2*)&Vt[(d * 8 + ((tp >> 2) ^ (d & 7))) * 8 + (tp & 3) * 2] = p;
      }
    }
    __syncthreads();
    // K and V^T fragments (shared across the 4 s-chunks)
    bf16x8 af[2][4], bv[2][4];
#pragma unroll
    for (int ks = 0; ks < 2; ++ks)
#pragma unroll
      for (int jc = 0; jc < 4; ++jc) {
        int row = jc * 16 + a_, q = ks * 4 + q4;
        af[ks][jc] = *(const bf16x8*)&Ks[(row * 8 + (q ^ (row & 7))) * 8];
        bv[ks][jc] = *(const bf16x8*)&Vt[(row * 8 + (q ^ (row & 7))) * 8];
      }
#pragma unroll
    for (int cc = 0; cc < 4; ++cc) {
      int sbase = (cc * 4 + w) * 16;
      // S^T = K Q^T : rows t = jc*16+q4*4+r, col s = sbase + a_
      floatx4 sc[4];
#pragma unroll
      for (int jc = 0; jc < 4; ++jc) sc[jc] = (floatx4)(0.0f);
#pragma unroll
      for (int ks = 0; ks < 2; ++ks) {
        int row = sbase + a_, q = ks * 4 + q4;
        bf16x8 bq = *(const bf16x8*)&Qs[(row * 8 + (q ^ (row & 7))) * 8];
#pragma unroll
        for (int jc = 0; jc < 4; ++jc)
          sc[jc] = __builtin_amdgcn_mfma_f32_16x16x32_bf16(af[ks][jc], bq,
                                                           sc[jc], 0, 0, 0);
      }
      // online softmax: per lane, all 16 values share column s = sbase+a_
      float mx = sc[0][0];
#pragma unroll
      for (int jc = 0; jc < 4; ++jc)
#pragma unroll
        for (int r = 0; r < 4; ++r) mx = fmaxf(mx, sc[jc][r]);
      mx = fmaxf(mx, __shfl_xor(mx, 16));
      mx = fmaxf(mx, __shfl_xor(mx, 32));
      float mnew = fmaxf(mrow[cc], mx);
      float alpha = __expf(mrow[cc] - mnew);
      mrow[cc] = mnew;
      float ps = 0.f;
      int prow = w * 16 + a_;
#pragma unroll
      for (int jc = 0; jc < 4; ++jc) {
        bf16x4 pb;
#pragma unroll
        for (int r = 0; r < 4; ++r) {
          float p = __expf(sc[jc][r] - mnew);
          ps += p;
          pb[r] = (__bf16)p;
        }
        int pc = jc * 2 + (q4 >> 1);
        *(bf16x4*)&Ps[(prow * 8 + (pc ^ (prow & 7))) * 8 + (q4 & 1) * 4] = pb;
      }
      ps += __shfl_xor(ps, 16);
      ps += __shfl_xor(ps, 32);
      lrow[cc] = lrow[cc] * alpha + ps;
      float aal[4];
#pragma unroll
      for (int r = 0; r < 4; ++r) aal[r] = __shfl(alpha, q4 * 4 + r);
#pragma unroll
      for (int jc = 0; jc < 4; ++jc) {
        floatx4 t = accO[cc][jc];
#pragma unroll
        for (int r = 0; r < 4; ++r) t[r] *= aal[r];
        accO[cc][jc] = t;
      }
      // O += P V  (Ps rows wave-private; same-wave RAW ordered via lgkmcnt)
#pragma unroll
      for (int ks = 0; ks < 2; ++ks) {
        int q = ks * 4 + q4;
        bf16x8 ap = *(const bf16x8*)&Ps[(prow * 8 + (q ^ (prow & 7))) * 8];
#pragma unroll
        for (int jc = 0; jc < 4; ++jc)
          accO[cc][jc] = __builtin_amdgcn_mfma_f32_16x16x32_bf16(
              ap, bv[ks][jc], accO[cc][jc], 0, 0, 0);
      }
    }
    __syncthreads();
  }
  // epilogue: row = s0+(cc*4+w)*16+q4*4+r, col = jc*16+a_  (into Q slice)
#pragma unroll
  for (int cc = 0; cc < 4; ++cc) {
    float inv = 1.f / lrow[cc];
    float linv[4];
#pragma unroll
    for (int r = 0; r < 4; ++r) linv[r] = __shfl(inv, q4 * 4 + r);
    int srow = s0 + (cc * 4 + w) * 16 + q4 * 4;
#pragma unroll
    for (int r = 0; r < 4; ++r)
#pragma unroll
      for (int jc = 0; jc < 4; ++jc)
        Qg[(size_t)(srow + r) * QS_ + jc * 16 + a_] =
            (__bf16)(accO[cc][jc][r] * linv[r]);
  }
}

// ---------------- add + l2norm: X = l2norm(X + MH), Ab = bf16(X) ----------
__global__ __launch_bounds__(256) void addnorm_kernel(
    float* __restrict__ X, const __bf16* __restrict__ MH, __bf16* __restrict__ Ab) {
  int row = blockIdx.x * 4 + (threadIdx.x >> 6);
  int ln = threadIdx.x & 63;
  size_t off = (size_t)row * E_ + ln * 8;
  float xv[8];
  *(float4*)&xv[0] = *(const float4*)(X + off);
  *(float4*)&xv[4] = *(const float4*)(X + off + 4);
  bf16x8 mh = *(const bf16x8*)(MH + off);
  float ss = 0.f;
#pragma unroll
  for (int j = 0; j < 8; ++j) {
    xv[j] += (float)mh[j];
    ss += xv[j] * xv[j];
  }
#pragma unroll
  for (int o = 1; o < 64; o <<= 1) ss += __shfl_xor(ss, o);
  float inv = rsqrtf(fmaxf(ss, 1e-12f));
  bf16x8 ob;
#pragma unroll
  for (int j = 0; j < 8; ++j) {
    xv[j] *= inv;
    ob[j] = (__bf16)xv[j];
  }
  *(float4*)(X + off) = *(float4*)&xv[0];
  *(float4*)(X + off + 4) = *(float4*)&xv[4];
  *(bf16x8*)(Ab + off) = ob;
}

// ---------------- conv-pool: pooled[b][l] = dot(X[b, 5l:5l+5, :], Wc)+bc ---
__global__ __launch_bounds__(256) void conv_pool_kernel(
    const float* __restrict__ X, const float* __restrict__ Wc,
    const float* __restrict__ bc, float* __restrict__ pooled) {
  int wid = blockIdx.x * 4 + (threadIdx.x >> 6);
  int ln = threadIdx.x & 63;
  int b = wid / LOUT_, l = wid % LOUT_;
  const float* xr = X + (size_t)b * S_ * E_ + (size_t)l * 5 * E_;
  float v = 0.f;
#pragma unroll
  for (int j = 0; j < 10; ++j) {
    int i = (j * 64 + ln) * 4;
    float4 x4 = *(const float4*)(xr + i);
    float4 w4 = *(const float4*)(Wc + i);
    v += x4.x * w4.x + x4.y * w4.y + x4.z * w4.z + x4.w * w4.w;
  }
#pragma unroll
  for (int o = 32; o >= 1; o >>= 1) v += __shfl_down(v, o);
  if (ln == 0) pooled[b * LOUT_ + l] = v + bc[0];
}

// ---------------- dense + softmax: out[b] = softmax(pooled[b] @ Wd + bd) ---
__global__ __launch_bounds__(256) void dense_softmax_kernel(
    const float* __restrict__ pooled, const float* __restrict__ Wd,
    const float* __restrict__ bd, float* __restrict__ out) {
  __shared__ float pl[LOUT_];
  __shared__ float red[256];
  __shared__ float lg[O_];
  int b = blockIdx.x, tid = threadIdx.x;
  if (tid < LOUT_) pl[tid] = pooled[b * LOUT_ + tid];
  __syncthreads();
  for (int o = tid; o < O_; o += 256) {
    float acc = bd[o];
#pragma unroll 6
    for (int l = 0; l < LOUT_; ++l) acc += pl[l] * Wd[l * O_ + o];
    lg[o] = acc;
  }
  __syncthreads();
  float mx = -3.0e38f;
  for (int o = tid; o < O_; o += 256) mx = fmaxf(mx, lg[o]);
  red[tid] = mx;
  __syncthreads();
  for (int s2 = 128; s2 > 0; s2 >>= 1) {
    if (tid < s2) red[tid] = fmaxf(red[tid], red[tid + s2]);
    __syncthreads();
  }
  mx = red[0];
  __syncthreads();
  float se = 0.f;
  for (int o = tid; o < O_; o += 256) {
    float e = __expf(lg[o] - mx);
    lg[o] = e;
    se += e;
  }
  red[tid] = se;
  __syncthreads();
  for (int s2 = 128; s2 > 0; s2 >>= 1) {
    if (tid < s2) red[tid] += red[tid + s2];
    __syncthreads();
  }
  float inv = 1.f / red[0];
  for (int o = tid; o < O_; o += 256) out[(size_t)b * O_ + o] = lg[o] * inv;
}

extern "C" void kernel_launch(void* const* d_in, const int* in_sizes, int n_in,
                              void* d_out, int out_size, void* d_ws, size_t ws_size,
                              hipStream_t stream) {
  const int* tokens = (const int*)d_in[0];
  const float* emb = (const float*)d_in[1];
  const float* Wq = (const float*)d_in[2];
  const float* bq = (const float*)d_in[3];
  const float* Wk = (const float*)d_in[4];
  const float* bk = (const float*)d_in[5];
  const float* Wv = (const float*)d_in[6];
  const float* bv = (const float*)d_in[7];
  const float* Wo = (const float*)d_in[8];
  const float* bo = (const float*)d_in[9];
  const float* W1 = (const float*)d_in[10];
  const float* b1 = (const float*)d_in[11];
  const float* W2 = (const float*)d_in[12];
  const float* b2 = (const float*)d_in[13];
  const float* Wc = (const float*)d_in[14];
  const float* bc = (const float*)d_in[15];
  const float* Wd = (const float*)d_in[16];
  const float* bd = (const float*)d_in[17];
  float* out = (float*)d_out;

  // ws layout (bytes):
  //  X f32        [0,   64M)
  //  Ab bf16      [64M, 96M)
  //  QKVb bf16    [96M, 192M)   [32768][1536]; FF1 out reuses [96M,160M)
  //  MH bf16      [192M,224M)   [32768][512]
  //  Wt bf16      [224M,240M)   qkv 6M | Wo 2M | W1 4M | W2 4M
  //  qkvbias f32  [240M, +24K)
  //  pooled f32   [..., +26.2K)
  char* ws = (char*)d_ws;
  float* X = (float*)ws;
  __bf16* Ab = (__bf16*)(ws + 67108864);
  __bf16* QKVb = (__bf16*)(ws + 100663296);
  __bf16* FF1b = QKVb;  // reuse (QKV dead after Wo gemm)
  __bf16* MHb = (__bf16*)(ws + 201326592);
  __bf16* Wt = (__bf16*)(ws + 234881024);
  __bf16* Wt_qkv = Wt;                 // [L][1536][512]
  __bf16* Wt_o = Wt + 3145728;         // [L][512][512]
  __bf16* Wt_1 = Wt + 4194304;         // [L][1024][512]
  __bf16* Wt_2 = Wt + 6291456;         // [L][512][1024]
  float* qkvbias = (float*)(ws + 251658240);
  float* pooled = qkvbias + 6144;

  dim3 tb(32, 8);
  transpose_bf16<<<dim3(2, 16, 32), tb, 0, stream>>>(Wq, Wt_qkv + 0,      512, 64, 32768, 786432, 32768);
  transpose_bf16<<<dim3(2, 16, 32), tb, 0, stream>>>(Wk, Wt_qkv + 262144, 512, 64, 32768, 786432, 32768);
  transpose_bf16<<<dim3(2, 16, 32), tb, 0, stream>>>(Wv, Wt_qkv + 524288, 512, 64, 32768, 786432, 32768);
  transpose_bf16<<<dim3(16, 16, 4), tb, 0, stream>>>(Wo, Wt_o, 512, 512, 262144, 0, 262144);
  transpose_bf16<<<dim3(32, 16, 4), tb, 0, stream>>>(W1, Wt_1, 512, 1024, 524288, 0, 524288);
  transpose_bf16<<<dim3(16, 32, 4), tb, 0, stream>>>(W2, Wt_2, 1024, 512, 524288, 0, 524288);
  bias_concat<<<dim3(24), dim3(256), 0, stream>>>(bq, bk, bv, qkvbias);

  embed_kernel<<<dim3(BS_ * E_ / 4 / 256), dim3(256), 0, stream>>>(tokens, emb, X, Ab);

  dim3 blk(256);
  dim3 gqkv(256, 12), g512(256, 4), g1024(256, 8);
  for (int i = 0; i < L_; ++i) {
    gemm_bf16<0, 0, 0, 1, 1><<<gqkv, blk, 0, stream>>>(
        Ab, Wt_qkv + (size_t)i * 786432, qkvbias + i * QS_, nullptr, nullptr,
        QKVb, QS_, 512, 512);
    attn_bf16<<<dim3(2, 8, 64), blk, 0, stream>>>(QKVb);
    gemm_bf16<0, 0, 0, 1, 0><<<g512, blk, 0, stream>>>(
        QKVb, Wt_o + (size_t)i * 262144, bo + i * E_, nullptr, nullptr, MHb,
        512, 512, QS_);
    addnorm_kernel<<<dim3(BS_ / 4), blk, 0, stream>>>(X, MHb, Ab);
    gemm_bf16<1, 0, 0, 1, 0><<<g1024, blk, 0, stream>>>(
        Ab, Wt_1 + (size_t)i * 524288, b1 + (size_t)i * 2 * E_, nullptr, nullptr,
        FF1b, 1024, 512, 512);
    gemm_bf16<0, 1, 1, 1, 0><<<g512, blk, 0, stream>>>(
        FF1b, Wt_2 + (size_t)i * 524288, b2 + (size_t)i * E_, X, X, Ab,
        512, 1024, 1024);
  }
  conv_pool_kernel<<<dim3(BS_ * LOUT_ / S_ / 4), blk, 0, stream>>>(X, Wc, bc, pooled);
  dense_softmax_kernel<<<dim3(B_), blk, 0, stream>>>(pooled, Wd, bd, out);
}

// Round 6
// 1462.445 us; speedup vs baseline: 8.0476x; 1.2118x over previous
//
#include <hip/hip_runtime.h>
#include <cstddef>

constexpr int B_ = 64, S_ = 512, E_ = 512, H_ = 8, D_ = 64, L_ = 4, O_ = 1000;
constexpr int BS_ = B_ * S_;        // 32768
constexpr int HD_ = H_ * D_;        // 512
constexpr int QS_ = 1536;           // fused QKV row stride
constexpr int LOUT_ = 102;
constexpr float SCALE_ = 0.04419417382415922f;  // 1/sqrt(512)

typedef __bf16 bf16x8 __attribute__((ext_vector_type(8)));
typedef __bf16 bf16x4 __attribute__((ext_vector_type(4)));
typedef __bf16 bf16x2 __attribute__((ext_vector_type(2)));
typedef float floatx4 __attribute__((ext_vector_type(4)));

__device__ inline void load16_lds(const __bf16* g, __bf16* l) {
  __builtin_amdgcn_global_load_lds(
      (const __attribute__((address_space(1))) void*)g,
      (__attribute__((address_space(3))) void*)l, 16, 0, 0);
}

// ---------------- weight transpose + bf16 convert ----------------
// in: fp32 [R][C] (z-slice at z*IZ). out: bf16 [C][R] at (z>>3)*OZL + (z&7)*OZH.
__global__ __launch_bounds__(256) void transpose_bf16(
    const float* __restrict__ in, __bf16* __restrict__ out,
    int R, int C, int IZ, int OZL, int OZH) {
  __shared__ float t[32][33];
  int z = blockIdx.z;
  const float* inz = in + (size_t)z * IZ;
  __bf16* outz = out + (size_t)(z >> 3) * OZL + (size_t)(z & 7) * OZH;
  int c0 = blockIdx.x * 32, r0 = blockIdx.y * 32;
  int x = threadIdx.x, y = threadIdx.y;  // (32,8)
#pragma unroll
  for (int j = 0; j < 32; j += 8) t[y + j][x] = inz[(size_t)(r0 + y + j) * C + c0 + x];
  __syncthreads();
#pragma unroll
  for (int j = 0; j < 32; j += 8)
    outz[(size_t)(c0 + y + j) * R + r0 + x] = (__bf16)t[x][y + j];
}

// ---------------- concat qkv bias: [L][1536] = bq|bk|bv ----------------
__global__ __launch_bounds__(256) void bias_concat(
    const float* __restrict__ bq, const float* __restrict__ bk,
    const float* __restrict__ bv, float* __restrict__ qkvb) {
  int idx = blockIdx.x * 256 + threadIdx.x;  // < 6144
  int l = idx / QS_, j = idx % QS_;
  float v;
  if (j < 512) v = bq[l * 512 + j];
  else if (j < 1024) v = bk[l * 512 + j - 512];
  else v = bv[l * 512 + j - 1024];
  qkvb[idx] = v;
}

// ---------------- embedding + mask -> X fp32 + Ab bf16 ----------------
__global__ __launch_bounds__(256) void embed_kernel(
    const int* __restrict__ tokens, const float* __restrict__ emb,
    float* __restrict__ X, __bf16* __restrict__ Ab) {
  int idx = blockIdx.x * 256 + threadIdx.x;  // float4 index
  int bs = idx >> 7;
  int e = (idx & 127) << 2;
  int tok = tokens[bs];
  float4 v;
  if (tok == 0) v = make_float4(0.f, 0.f, 0.f, 0.f);
  else v = *(const float4*)(emb + (size_t)tok * E_ + e);
  size_t off = (size_t)bs * E_ + e;
  *(float4*)(X + off) = v;
  bf16x4 b;
  b[0] = (__bf16)v.x; b[1] = (__bf16)v.y; b[2] = (__bf16)v.z; b[3] = (__bf16)v.w;
  *(bf16x4*)(Ab + off) = b;
}

// ---------------- bf16 MFMA GEMM (m97-style, BK=64, xor-swizzled LDS) ------
// C[M,N] = act(A[M,K] @ B + bias (+ Rsd)).  Bt is [N][K] (B transposed).
// 1D grid of (Mt*Nt) blocks, XCD-aware swizzle: id&7 picks a private m-range
// (Mt/8 tiles); within it, n iterates fastest over chunks of 2 m-tiles, so
// the concurrent per-XCD L2 footprint is 2 A-tiles + the whole B slab (<4MB).
// MFMA operands swapped (D holds C^T fragments): lane owns row m = a_,
// 4 consecutive cols n = jc*16 + q4*4 + r  -> vectorized epilogue.
// bf16 C staged through LDS (pad 136) -> 256B-contiguous coalesced stores.
template <int RELU, int RES, int OUTF, int OUTB, int SCQ, int KITER>
__global__ __launch_bounds__(256) void gemm_bf16(
    const __bf16* __restrict__ A, const __bf16* __restrict__ Bt,
    const float* __restrict__ bias, const float* __restrict__ Rsd,
    float* __restrict__ Cf, __bf16* __restrict__ Cb, int N, int lda, int Nt) {
  __shared__ __align__(16) __bf16 smem[128 * 136];  // As | Bs overlay, then Cs
  __bf16* As = smem;
  __bf16* Bs = smem + 8192;
  int tid = threadIdx.x;
  int lane = tid & 63, w = tid >> 6;
  // XCD-aware swizzle
  int Mt8 = (int)(gridDim.x / Nt) >> 3;       // m-tiles per XCD range
  int xcd = blockIdx.x & 7;
  int j = blockIdx.x >> 3;
  int rr = j % (2 * Nt), chunk = j / (2 * Nt);
  int mt = xcd * Mt8 + chunk * 2 + (rr & 1);
  int nt = rr >> 1;
  int m0 = mt * 128, n0 = nt * 128;
  int q4 = lane >> 4, a_ = lane & 15;
  floatx4 acc[4][4];
#pragma unroll
  for (int i = 0; i < 4; ++i)
#pragma unroll
    for (int jj = 0; jj < 4; ++jj) acc[i][jj] = (floatx4)(0.0f);

  for (int kk = 0; kk < KITER; ++kk) {
    int k0 = kk * 64;
#pragma unroll
    for (int jj = 0; jj < 4; ++jj) {
      int ci = (jj * 4 + w) * 64 + lane;
      int row = ci >> 3, c = ci & 7, q = c ^ (row & 7);
      load16_lds(A + (size_t)(m0 + row) * lda + k0 + q * 8, As + (size_t)(jj * 4 + w) * 512);
    }
#pragma unroll
    for (int jj = 0; jj < 4; ++jj) {
      int ci = (jj * 4 + w) * 64 + lane;
      int row = ci >> 3, c = ci & 7, q = c ^ (row & 7);
      load16_lds(Bt + (size_t)(n0 + row) * (KITER * 64) + k0 + q * 8,
                 Bs + (size_t)(jj * 4 + w) * 512);
    }
    __syncthreads();
#pragma unroll
    for (int ks = 0; ks < 2; ++ks) {
      bf16x8 af[4], bfr[4];
#pragma unroll
      for (int i = 0; i < 4; ++i) {
        int row = (w & 1) * 64 + i * 16 + a_;
        int q = ks * 4 + q4;
        af[i] = *(const bf16x8*)&As[(row * 8 + (q ^ (row & 7))) * 8];
      }
#pragma unroll
      for (int jc = 0; jc < 4; ++jc) {
        int row = (w >> 1) * 64 + jc * 16 + a_;
        int q = ks * 4 + q4;
        bfr[jc] = *(const bf16x8*)&Bs[(row * 8 + (q ^ (row & 7))) * 8];
      }
#pragma unroll
      for (int i = 0; i < 4; ++i)
#pragma unroll
        for (int jc = 0; jc < 4; ++jc)
          acc[i][jc] = __builtin_amdgcn_mfma_f32_16x16x32_bf16(bfr[jc], af[i],
                                                               acc[i][jc], 0, 0, 0);
    }
    __syncthreads();
  }
  // ---- epilogue: vectorized, bf16 staged via LDS ----
#pragma unroll
  for (int i = 0; i < 4; ++i) {
    int ml = (w & 1) * 64 + i * 16 + a_;
    int m = m0 + ml;
#pragma unroll
    for (int jc = 0; jc < 4; ++jc) {
      int nl = (w >> 1) * 64 + jc * 16 + q4 * 4;
      int n = n0 + nl;
      float4 bi = *(const float4*)(bias + n);
      floatx4 v = acc[i][jc];
      v[0] += bi.x; v[1] += bi.y; v[2] += bi.z; v[3] += bi.w;
      if (SCQ) { if (n < 512) v *= SCALE_; }
      if (RES) {
        float4 rv = *(const float4*)(Rsd + (size_t)m * N + n);
        v[0] += rv.x; v[1] += rv.y; v[2] += rv.z; v[3] += rv.w;
      }
      if (RELU) {
#pragma unroll
        for (int r = 0; r < 4; ++r) v[r] = fmaxf(v[r], 0.f);
      }
      if (OUTF) {
        float4 o = make_float4(v[0], v[1], v[2], v[3]);
        *(float4*)(Cf + (size_t)m * N + n) = o;
      }
      if (OUTB) {
        bf16x4 ob;
#pragma unroll
        for (int r = 0; r < 4; ++r) ob[r] = (__bf16)v[r];
        *(bf16x4*)&smem[ml * 136 + nl] = ob;
      }
    }
  }
  if (OUTB) {
    __syncthreads();
#pragma unroll
    for (int it = 0; it < 8; ++it) {
      int cid = it * 256 + tid;
      int row = cid >> 4, c8 = cid & 15;
      bf16x8 val = *(const bf16x8*)&smem[row * 136 + c8 * 8];
      *(bf16x8*)(Cb + (size_t)(m0 + row) * N + n0 + c8 * 8) = val;
    }
  }
}

// ---------------- MFMA flash attention v2 (S^T layout, swizzled LDS) ------
// block = (b, h, 256-row Q slab); 4 waves; wave w owns s-chunks (cc*4+w)*16.
// Q pre-scaled by 1/sqrt(E) in QKV gemm epilogue. Heads written in-place
// over the Q slice (only this block touches its (b,h,s-slab) Q slice).
__global__ __launch_bounds__(256, 2) void attn_bf16(__bf16* __restrict__ QKV) {
  __shared__ __align__(16) __bf16 Qs[256 * 64];  // swizzled chunks
  __shared__ __align__(16) __bf16 Ks[64 * 64];   // swizzled
  __shared__ __align__(16) __bf16 Vt[64 * 64];   // V^T [d][t], swizzled
  __shared__ __align__(16) __bf16 Ps[64 * 64];   // P [s][t], swizzled
  int tid = threadIdx.x, lane = tid & 63, w = tid >> 6;
  int q4 = lane >> 4, a_ = lane & 15;
  int s0 = blockIdx.x * 256, h = blockIdx.y, b = blockIdx.z;
  size_t rowbase = (size_t)b * S_ * QS_ + h * 64;
  __bf16* Qg = QKV + rowbase;
  const __bf16* Kg = QKV + rowbase + 512;
  const __bf16* Vg = QKV + rowbase + 1024;
  // stage Q slab (256 rows), swizzled
#pragma unroll
  for (int j = 0; j < 8; ++j) {
    int ci = j * 256 + w * 64 + lane;
    int row = ci >> 3, c = ci & 7, q = c ^ (row & 7);
    load16_lds(Qg + (size_t)(s0 + row) * QS_ + q * 8, Qs + (j * 256 + w * 64) * 8);
  }
  float mrow[4], lrow[4];
  floatx4 accO[4][4];
#pragma unroll
  for (int cc = 0; cc < 4; ++cc) {
    mrow[cc] = -3.0e38f; lrow[cc] = 0.f;
#pragma unroll
    for (int jc = 0; jc < 4; ++jc) accO[cc][jc] = (floatx4)(0.0f);
  }

  for (int t0 = 0; t0 < S_; t0 += 64) {
    // stage K tile, swizzled
#pragma unroll
    for (int j = 0; j < 2; ++j) {
      int ci = j * 256 + w * 64 + lane;
      int row = ci >> 3, c = ci & 7, q = c ^ (row & 7);
      load16_lds(Kg + (size_t)(t0 + row) * QS_ + q * 8, Ks + (j * 256 + w * 64) * 8);
    }
    // stage V transposed -> Vt[d][t], swizzled chunks
    {
      int tp = tid & 31, dg = tid >> 5;
      bf16x8 v0 = *(const bf16x8*)(Vg + (size_t)(t0 + 2 * tp) * QS_ + dg * 8);
      bf16x8 v1 = *(const bf16x8*)(Vg + (size_t)(t0 + 2 * tp + 1) * QS_ + dg * 8);
#pragma unroll
      for (int x = 0; x < 8; ++x) {
        int d = dg * 8 + x;
        bf16x2 p; p[0] = v0[x]; p[1] = v1[x];
        *(bf16x2*)&Vt[(d * 8 + ((tp >> 2) ^ (d & 7))) * 8 + (tp & 3) * 2] = p;
      }
    }
    __syncthreads();
    // K and V^T fragments (shared across the 4 s-chunks)
    bf16x8 af[2][4], bv[2][4];
#pragma unroll
    for (int ks = 0; ks < 2; ++ks)
#pragma unroll
      for (int jc = 0; jc < 4; ++jc) {
        int row = jc * 16 + a_, q = ks * 4 + q4;
        af[ks][jc] = *(const bf16x8*)&Ks[(row * 8 + (q ^ (row & 7))) * 8];
        bv[ks][jc] = *(const bf16x8*)&Vt[(row * 8 + (q ^ (row & 7))) * 8];
      }
#pragma unroll
    for (int cc = 0; cc < 4; ++cc) {
      int sbase = (cc * 4 + w) * 16;
      // S^T = K Q^T : rows t = jc*16+q4*4+r, col s = sbase + a_
      floatx4 sc[4];
#pragma unroll
      for (int jc = 0; jc < 4; ++jc) sc[jc] = (floatx4)(0.0f);
#pragma unroll
      for (int ks = 0; ks < 2; ++ks) {
        int row = sbase + a_, q = ks * 4 + q4;
        bf16x8 bq = *(const bf16x8*)&Qs[(row * 8 + (q ^ (row & 7))) * 8];
#pragma unroll
        for (int jc = 0; jc < 4; ++jc)
          sc[jc] = __builtin_amdgcn_mfma_f32_16x16x32_bf16(af[ks][jc], bq,
                                                           sc[jc], 0, 0, 0);
      }
      // online softmax: per lane, all 16 values share column s = sbase+a_
      float mx = sc[0][0];
#pragma unroll
      for (int jc = 0; jc < 4; ++jc)
#pragma unroll
        for (int r = 0; r < 4; ++r) mx = fmaxf(mx, sc[jc][r]);
      mx = fmaxf(mx, __shfl_xor(mx, 16));
      mx = fmaxf(mx, __shfl_xor(mx, 32));
      float mnew = fmaxf(mrow[cc], mx);
      float alpha = __expf(mrow[cc] - mnew);
      mrow[cc] = mnew;
      float ps = 0.f;
      int prow = w * 16 + a_;
#pragma unroll
      for (int jc = 0; jc < 4; ++jc) {
        bf16x4 pb;
#pragma unroll
        for (int r = 0; r < 4; ++r) {
          float p = __expf(sc[jc][r] - mnew);
          ps += p;
          pb[r] = (__bf16)p;
        }
        int pc = jc * 2 + (q4 >> 1);
        *(bf16x4*)&Ps[(prow * 8 + (pc ^ (prow & 7))) * 8 + (q4 & 1) * 4] = pb;
      }
      ps += __shfl_xor(ps, 16);
      ps += __shfl_xor(ps, 32);
      lrow[cc] = lrow[cc] * alpha + ps;
      float aal[4];
#pragma unroll
      for (int r = 0; r < 4; ++r) aal[r] = __shfl(alpha, q4 * 4 + r);
#pragma unroll
      for (int jc = 0; jc < 4; ++jc) {
        floatx4 t = accO[cc][jc];
#pragma unroll
        for (int r = 0; r < 4; ++r) t[r] *= aal[r];
        accO[cc][jc] = t;
      }
      // O += P V  (Ps rows wave-private; same-wave LDS RAW ordered via lgkmcnt)
#pragma unroll
      for (int ks = 0; ks < 2; ++ks) {
        int q = ks * 4 + q4;
        bf16x8 ap = *(const bf16x8*)&Ps[(prow * 8 + (q ^ (prow & 7))) * 8];
#pragma unroll
        for (int jc = 0; jc < 4; ++jc)
          accO[cc][jc] = __builtin_amdgcn_mfma_f32_16x16x32_bf16(
              ap, bv[ks][jc], accO[cc][jc], 0, 0, 0);
      }
    }
    __syncthreads();
  }
  // epilogue: row = s0+(cc*4+w)*16+q4*4+r, col = jc*16+a_  (into Q slice)
#pragma unroll
  for (int cc = 0; cc < 4; ++cc) {
    float inv = 1.f / lrow[cc];
    float linv[4];
#pragma unroll
    for (int r = 0; r < 4; ++r) linv[r] = __shfl(inv, q4 * 4 + r);
    int srow = s0 + (cc * 4 + w) * 16 + q4 * 4;
#pragma unroll
    for (int r = 0; r < 4; ++r)
#pragma unroll
      for (int jc = 0; jc < 4; ++jc)
        Qg[(size_t)(srow + r) * QS_ + jc * 16 + a_] =
            (__bf16)(accO[cc][jc][r] * linv[r]);
  }
}

// ---------------- add + l2norm: X = l2norm(X + MH), Ab = bf16(X) ----------
__global__ __launch_bounds__(256) void addnorm_kernel(
    float* __restrict__ X, const __bf16* __restrict__ MH, __bf16* __restrict__ Ab) {
  int row = blockIdx.x * 4 + (threadIdx.x >> 6);
  int ln = threadIdx.x & 63;
  size_t off = (size_t)row * E_ + ln * 8;
  float xv[8];
  *(float4*)&xv[0] = *(const float4*)(X + off);
  *(float4*)&xv[4] = *(const float4*)(X + off + 4);
  bf16x8 mh = *(const bf16x8*)(MH + off);
  float ss = 0.f;
#pragma unroll
  for (int j = 0; j < 8; ++j) {
    xv[j] += (float)mh[j];
    ss += xv[j] * xv[j];
  }
#pragma unroll
  for (int o = 1; o < 64; o <<= 1) ss += __shfl_xor(ss, o);
  float inv = rsqrtf(fmaxf(ss, 1e-12f));
  bf16x8 ob;
#pragma unroll
  for (int j = 0; j < 8; ++j) {
    xv[j] *= inv;
    ob[j] = (__bf16)xv[j];
  }
  *(float4*)(X + off) = *(float4*)&xv[0];
  *(float4*)(X + off + 4) = *(float4*)&xv[4];
  *(bf16x8*)(Ab + off) = ob;
}

// ---------------- conv-pool: pooled[b][l] = dot(X[b, 5l:5l+5, :], Wc)+bc ---
__global__ __launch_bounds__(256) void conv_pool_kernel(
    const float* __restrict__ X, const float* __restrict__ Wc,
    const float* __restrict__ bc, float* __restrict__ pooled) {
  int wid = blockIdx.x * 4 + (threadIdx.x >> 6);
  int ln = threadIdx.x & 63;
  int b = wid / LOUT_, l = wid % LOUT_;
  const float* xr = X + (size_t)b * S_ * E_ + (size_t)l * 5 * E_;
  float v = 0.f;
#pragma unroll
  for (int j = 0; j < 10; ++j) {
    int i = (j * 64 + ln) * 4;
    float4 x4 = *(const float4*)(xr + i);
    float4 w4 = *(const float4*)(Wc + i);
    v += x4.x * w4.x + x4.y * w4.y + x4.z * w4.z + x4.w * w4.w;
  }
#pragma unroll
  for (int o = 32; o >= 1; o >>= 1) v += __shfl_down(v, o);
  if (ln == 0) pooled[b * LOUT_ + l] = v + bc[0];
}

// ---------------- dense + softmax: out[b] = softmax(pooled[b] @ Wd + bd) ---
__global__ __launch_bounds__(256) void dense_softmax_kernel(
    const float* __restrict__ pooled, const float* __restrict__ Wd,
    const float* __restrict__ bd, float* __restrict__ out) {
  __shared__ float pl[LOUT_];
  __shared__ float red[256];
  __shared__ float lg[O_];
  int b = blockIdx.x, tid = threadIdx.x;
  if (tid < LOUT_) pl[tid] = pooled[b * LOUT_ + tid];
  __syncthreads();
  for (int o = tid; o < O_; o += 256) {
    float acc = bd[o];
#pragma unroll 6
    for (int l = 0; l < LOUT_; ++l) acc += pl[l] * Wd[l * O_ + o];
    lg[o] = acc;
  }
  __syncthreads();
  float mx = -3.0e38f;
  for (int o = tid; o < O_; o += 256) mx = fmaxf(mx, lg[o]);
  red[tid] = mx;
  __syncthreads();
  for (int s2 = 128; s2 > 0; s2 >>= 1) {
    if (tid < s2) red[tid] = fmaxf(red[tid], red[tid + s2]);
    __syncthreads();
  }
  mx = red[0];
  __syncthreads();
  float se = 0.f;
  for (int o = tid; o < O_; o += 256) {
    float e = __expf(lg[o] - mx);
    lg[o] = e;
    se += e;
  }
  red[tid] = se;
  __syncthreads();
  for (int s2 = 128; s2 > 0; s2 >>= 1) {
    if (tid < s2) red[tid] += red[tid + s2];
    __syncthreads();
  }
  float inv = 1.f / red[0];
  for (int o = tid; o < O_; o += 256) out[(size_t)b * O_ + o] = lg[o] * inv;
}

extern "C" void kernel_launch(void* const* d_in, const int* in_sizes, int n_in,
                              void* d_out, int out_size, void* d_ws, size_t ws_size,
                              hipStream_t stream) {
  const int* tokens = (const int*)d_in[0];
  const float* emb = (const float*)d_in[1];
  const float* Wq = (const float*)d_in[2];
  const float* bq = (const float*)d_in[3];
  const float* Wk = (const float*)d_in[4];
  const float* bk = (const float*)d_in[5];
  const float* Wv = (const float*)d_in[6];
  const float* bv = (const float*)d_in[7];
  const float* Wo = (const float*)d_in[8];
  const float* bo = (const float*)d_in[9];
  const float* W1 = (const float*)d_in[10];
  const float* b1 = (const float*)d_in[11];
  const float* W2 = (const float*)d_in[12];
  const float* b2 = (const float*)d_in[13];
  const float* Wc = (const float*)d_in[14];
  const float* bc = (const float*)d_in[15];
  const float* Wd = (const float*)d_in[16];
  const float* bd = (const float*)d_in[17];
  float* out = (float*)d_out;

  // ws layout (bytes):
  //  X f32        [0,   64M)
  //  Ab bf16      [64M, 96M)
  //  QKVb bf16    [96M, 192M)   [32768][1536]; FF1 out reuses [96M,160M)
  //  MH bf16      [192M,224M)   [32768][512]
  //  Wt bf16      [224M,240M)   qkv 6M | Wo 2M | W1 4M | W2 4M
  //  qkvbias f32  [240M, +24K)
  //  pooled f32   [..., +26.2K)
  char* ws = (char*)d_ws;
  float* X = (float*)ws;
  __bf16* Ab = (__bf16*)(ws + 67108864);
  __bf16* QKVb = (__bf16*)(ws + 100663296);
  __bf16* FF1b = QKVb;  // reuse (QKV dead after Wo gemm)
  __bf16* MHb = (__bf16*)(ws + 201326592);
  __bf16* Wt = (__bf16*)(ws + 234881024);
  __bf16* Wt_qkv = Wt;                 // [L][1536][512]
  __bf16* Wt_o = Wt + 3145728;         // [L][512][512]
  __bf16* Wt_1 = Wt + 4194304;         // [L][1024][512]
  __bf16* Wt_2 = Wt + 6291456;         // [L][512][1024]
  float* qkvbias = (float*)(ws + 251658240);
  float* pooled = qkvbias + 6144;

  dim3 tb(32, 8);
  transpose_bf16<<<dim3(2, 16, 32), tb, 0, stream>>>(Wq, Wt_qkv + 0,      512, 64, 32768, 786432, 32768);
  transpose_bf16<<<dim3(2, 16, 32), tb, 0, stream>>>(Wk, Wt_qkv + 262144, 512, 64, 32768, 786432, 32768);
  transpose_bf16<<<dim3(2, 16, 32), tb, 0, stream>>>(Wv, Wt_qkv + 524288, 512, 64, 32768, 786432, 32768);
  transpose_bf16<<<dim3(16, 16, 4), tb, 0, stream>>>(Wo, Wt_o, 512, 512, 262144, 0, 262144);
  transpose_bf16<<<dim3(32, 16, 4), tb, 0, stream>>>(W1, Wt_1, 512, 1024, 524288, 0, 524288);
  transpose_bf16<<<dim3(16, 32, 4), tb, 0, stream>>>(W2, Wt_2, 1024, 512, 524288, 0, 524288);
  bias_concat<<<dim3(24), dim3(256), 0, stream>>>(bq, bk, bv, qkvbias);

  embed_kernel<<<dim3(BS_ * E_ / 4 / 256), dim3(256), 0, stream>>>(tokens, emb, X, Ab);

  dim3 blk(256);
  for (int i = 0; i < L_; ++i) {
    gemm_bf16<0, 0, 0, 1, 1, 8><<<dim3(256 * 12), blk, 0, stream>>>(
        Ab, Wt_qkv + (size_t)i * 786432, qkvbias + i * QS_, nullptr, nullptr,
        QKVb, QS_, 512, 12);
    attn_bf16<<<dim3(2, 8, 64), blk, 0, stream>>>(QKVb);
    gemm_bf16<0, 0, 0, 1, 0, 8><<<dim3(256 * 4), blk, 0, stream>>>(
        QKVb, Wt_o + (size_t)i * 262144, bo + i * E_, nullptr, nullptr, MHb,
        512, QS_, 4);
    addnorm_kernel<<<dim3(BS_ / 4), blk, 0, stream>>>(X, MHb, Ab);
    gemm_bf16<1, 0, 0, 1, 0, 8><<<dim3(256 * 8), blk, 0, stream>>>(
        Ab, Wt_1 + (size_t)i * 524288, b1 + (size_t)i * 2 * E_, nullptr, nullptr,
        FF1b, 1024, 512, 8);
    gemm_bf16<0, 1, 1, 1, 0, 16><<<dim3(256 * 4), blk, 0, stream>>>(
        FF1b, Wt_2 + (size_t)i * 524288, b2 + (size_t)i * E_, X, X, Ab,
        512, 1024, 4);
  }
  conv_pool_kernel<<<dim3(BS_ * LOUT_ / S_ / 4), blk, 0, stream>>>(X, Wc, bc, pooled);
  dense_softmax_kernel<<<dim3(B_), blk, 0, stream>>>(pooled, Wd, bd, out);
}